// Round 16
// baseline (670.650 us; speedup 1.0000x reference)
//
#include <hip/hip_runtime.h>
#include <math.h>

// Problem constants (fixed by the reference; k input is ignored, always 16)
#define BN 16384
#define DK 128
#define HN 4
#define CN 64
#define HC 256
#define TK 16
#define CAP 512              // candidate buffer capacity per row

// ---- streamed GEMM geometry: 128-row panel x 1024-col strip per block
#define GSPLIT 16            // column strips
#define GSPAN  1024          // cols per strip (= one gmax group)
#define GBC    128           // cols per B tile (32 KB)
#define GNT    (GSPAN / GBC) // 8 steps per strip

// ---- old fallback pipeline geometry
#define NSTRIP 2
#define SCOLS (BN / NSTRIP)
#define RPB 64
#define CT 64

typedef float4 f4;
typedef __attribute__((ext_vector_type(8))) short short8;
typedef __attribute__((ext_vector_type(4))) float f32x4;

__device__ __forceinline__ unsigned bf_rne(float f) {
  unsigned u = __float_as_uint(f);
  u += 0x7fffu + ((u >> 16) & 1u);
  return u >> 16;
}

// order-preserving float->uint map (monotone for all finite floats)
__device__ __forceinline__ unsigned fmap(float f) {
  unsigned b = __float_as_uint(f);
  return (b & 0x80000000u) ? ~b : (b | 0x80000000u);
}

// async global->LDS, 16B per lane (dest is wave-uniform base + lane*16)
__device__ __forceinline__ void gload16(const unsigned short* g,
                                        unsigned short* l) {
  __builtin_amdgcn_global_load_lds(
      (const __attribute__((address_space(1))) unsigned int*)g,
      (__attribute__((address_space(3))) unsigned int*)l, 16, 0, 0);
}

// ---------------- init: deg=1, cur=0, gmaxu=0 (re-init every call)
__global__ __launch_bounds__(256) void k_init(int* deg, int* cur,
                                              unsigned* gmaxu) {
  int i = blockIdx.x * 256 + threadIdx.x;
  if (i < BN) { deg[i] = 1; cur[i] = 0; }
  if (i < BN * 16) gmaxu[i] = 0u;    // mapped ~ -inf
}

// ---------------- x_l = x@W_l + b_l ; x_r = x@W_r + b_r  (fp32, 16 rows/block)
__global__ __launch_bounds__(256) void k_lin(const float* __restrict__ x,
    const float* __restrict__ Wl, const float* __restrict__ bl,
    const float* __restrict__ Wr, const float* __restrict__ br,
    float* __restrict__ xl, float* __restrict__ xr) {
  __shared__ __align__(16) float xst[DK][16];
  int tid = threadIdx.x;
  int r0 = blockIdx.x * 16;
  for (int i = 0; i < 2; ++i) {
    int s = tid + i * 256;
    int r = s >> 5, kq = s & 31;
    f4 v = *(const f4*)&x[(size_t)(r0 + r) * DK + kq * 4];
    xst[kq*4+0][r] = v.x; xst[kq*4+1][r] = v.y;
    xst[kq*4+2][r] = v.z; xst[kq*4+3][r] = v.w;
  }
  __syncthreads();
  float al[16], ar[16];
  #pragma unroll
  for (int r = 0; r < 16; ++r) { al[r] = 0.f; ar[r] = 0.f; }
  for (int k = 0; k < DK; ++k) {
    float wl = Wl[k * HC + tid];
    float wr = Wr[k * HC + tid];
    float xv[16];
    *(f4*)&xv[0]  = *(const f4*)&xst[k][0];
    *(f4*)&xv[4]  = *(const f4*)&xst[k][4];
    *(f4*)&xv[8]  = *(const f4*)&xst[k][8];
    *(f4*)&xv[12] = *(const f4*)&xst[k][12];
    #pragma unroll
    for (int r = 0; r < 16; ++r) { al[r] += xv[r] * wl; ar[r] += xv[r] * wr; }
  }
  float bbl = bl[tid], bbr = br[tid];
  #pragma unroll
  for (int r = 0; r < 16; ++r) {
    xl[(size_t)(r0 + r) * HC + tid] = al[r] + bbl;
    xr[(size_t)(r0 + r) * HC + tid] = ar[r] + bbr;
  }
}

// ---------------- x (fp32) -> x_bf (bf16, RNE)
__global__ __launch_bounds__(256) void k_cvt(const float* __restrict__ x,
                                             unsigned short* __restrict__ xbf) {
  size_t base = (size_t)(blockIdx.x * 256 + threadIdx.x) * 8;
  f4 a = *(const f4*)&x[base];
  f4 b = *(const f4*)&x[base + 4];
  uint4 o;
  o.x = bf_rne(a.x) | (bf_rne(a.y) << 16);
  o.y = bf_rne(a.z) | (bf_rne(a.w) << 16);
  o.z = bf_rne(b.x) | (bf_rne(b.y) << 16);
  o.w = bf_rne(b.z) | (bf_rne(b.w) << 16);
  *(uint4*)&xbf[base] = o;
}

// ---------------- streamed MFMA scorer: round-10 schedule. ROUND-16 CHANGE:
// A fragments are NO LONGER hoisted into af[4][4] (64 VGPRs live across all
// 8 steps). Rounds 14/15 proved the kernel is scratch-BW-bound: 513 MB
// traffic/dispatch (true data ~60 MB) at 2.6 TB/s = the whole 197 us, and
// raising launch bounds was a no-op (unified VGPR/AGPR file already full:
// 128 arch VGPR + MFMA AGPRs). Fix: shrink the live set. A-fragments are
// re-read from As per step per ks-slice (afq[4], 16 regs) — As stays
// resident in LDS anyway; +16 ds_read_b128/step/wave hides under 16 MFMAs.
// Scores bitwise identical: same LDS bytes, same ks-ascending MFMA chain.
// Per block: 128-row panel vs 1024-col strip, 8 steps of 128 cols, 8 waves
// (2x4 of 64x32 tiles). B tiles double-buffered with global_load_lds issued
// before compute, one __syncthreads per step.
// acc[m][n][r]: row = q0+64wm+16m+4th+r, col = c0+128t+32wn+16n+tq.
// MODE 0: runtime loop, lane-local running max, block-end reduce.
// MODE 1: fully-unrolled loop builds per-step 32-bit hit masks in
// statically-indexed registers; atomicAdd+store flush AFTER the loop.
template <int MODE>
__global__ __launch_bounds__(512, 1) void k_gemm_t(
    const unsigned short* __restrict__ xbf, unsigned* __restrict__ gmaxu,
    const unsigned* __restrict__ tau_u, int* __restrict__ cnt,
    int* __restrict__ cand) {
  __shared__ __align__(16) unsigned short As[128 * DK];
  __shared__ __align__(16) unsigned short Bs0[128 * DK];
  __shared__ __align__(16) unsigned short Bs1[128 * DK];
  __shared__ float red[4][128];
  int tid = threadIdx.x;
  int q0 = blockIdx.y * 128;
  int c0 = blockIdx.x * GSPAN;
  int lane = tid & 63;
  int wid = tid >> 6;
  int wm = wid & 1, wn = wid >> 1;
  int tq = lane & 15, th = lane >> 4;

  // t-invariant staging geometry: slot = tid + i*512 -> (row, 16B chunk)
  // source chunk pre-swizzled so linear LDS dest == XOR-swizzled layout
  int soff[4];       // element offset within a 128-row tile
  #pragma unroll
  for (int i = 0; i < 4; ++i) {
    int slot = tid + i * 512;
    int row = slot >> 4, c8 = slot & 15;
    soff[i] = row * DK + ((c8 ^ (row & 7)) * 8);
  }
  // prologue: stage A panel + B tile 0
  #pragma unroll
  for (int i = 0; i < 4; ++i)
    gload16(&xbf[(size_t)q0 * DK + soff[i]], &As[(tid + i * 512) * 8]);
  #pragma unroll
  for (int i = 0; i < 4; ++i)
    gload16(&xbf[(size_t)c0 * DK + soff[i]], &Bs0[(tid + i * 512) * 8]);
  __syncthreads();   // drains vmcnt -> A and B0 resident

  float gmx[4][4];   // MODE 0: lane-local running max
  float tauf[4][4];  // MODE 1: float-domain threshold
  if constexpr (MODE == 0) {
    #pragma unroll
    for (int m = 0; m < 4; ++m)
      #pragma unroll
      for (int r = 0; r < 4; ++r) gmx[m][r] = -3.0e38f;
  } else {
    #pragma unroll
    for (int m = 0; m < 4; ++m)
      #pragma unroll
      for (int r = 0; r < 4; ++r) {
        unsigned tu = tau_u[q0 + 64*wm + 16*m + 4*th + r];
        tauf[m][r] = __uint_as_float(
            (tu >= 0x80000000u) ? (tu ^ 0x80000000u) : ~tu);
      }
  }

  if constexpr (MODE == 0) {
    // ---- runtime loop (round-10 schedule; A-frags re-read per ks)
    unsigned short* Bc = Bs0;
    unsigned short* Bn = Bs1;
    for (int t = 0; t < GNT; ++t) {
      if (t + 1 < GNT) {
        size_t gb = (size_t)(c0 + (t + 1) * GBC) * DK;
        #pragma unroll
        for (int i = 0; i < 4; ++i)
          gload16(&xbf[gb + soff[i]], &Bn[(tid + i * 512) * 8]);
      }
      short8 bfr[2][4];
      #pragma unroll
      for (int n = 0; n < 2; ++n) {
        int rb = 32 * wn + 16 * n + tq;
        #pragma unroll
        for (int ks = 0; ks < 4; ++ks)
          bfr[n][ks] = *(const short8*)&Bc[rb * DK +
                          (((ks*4+th) ^ (rb & 7)) * 8)];
      }
      f32x4 acc[4][2];
      #pragma unroll
      for (int m = 0; m < 4; ++m)
        #pragma unroll
        for (int n = 0; n < 2; ++n) {
          acc[m][n][0] = 0.f; acc[m][n][1] = 0.f;
          acc[m][n][2] = 0.f; acc[m][n][3] = 0.f;
        }
      #pragma unroll
      for (int ks = 0; ks < 4; ++ks) {
        short8 afq[4];
        #pragma unroll
        for (int m = 0; m < 4; ++m) {
          int ra = 64 * wm + 16 * m + tq;
          afq[m] = *(const short8*)&As[ra * DK +
                       (((ks*4+th) ^ (ra & 7)) * 8)];
        }
        #pragma unroll
        for (int m = 0; m < 4; ++m)
          #pragma unroll
          for (int n = 0; n < 2; ++n)
            acc[m][n] = __builtin_amdgcn_mfma_f32_16x16x32_bf16(
                afq[m], bfr[n][ks], acc[m][n], 0, 0, 0);
      }
      #pragma unroll
      for (int m = 0; m < 4; ++m)
        #pragma unroll
        for (int r = 0; r < 4; ++r)
          gmx[m][r] = fmaxf(gmx[m][r], fmaxf(acc[m][0][r], acc[m][1][r]));
      __syncthreads();
      unsigned short* tb = Bc; Bc = Bn; Bn = tb;
    }
    // reduce over tq lanes, then across wn waves via LDS; plain store
    #pragma unroll
    for (int m = 0; m < 4; ++m)
      #pragma unroll
      for (int r = 0; r < 4; ++r) {
        float v = gmx[m][r];
        #pragma unroll
        for (int w = 1; w < 16; w <<= 1) v = fmaxf(v, __shfl_xor(v, w, 64));
        if (tq == 0) red[wn][64*wm + 16*m + 4*th + r] = v;
      }
    __syncthreads();
    if (tid < 128) {
      float v = fmaxf(fmaxf(red[0][tid], red[1][tid]),
                      fmaxf(red[2][tid], red[3][tid]));
      gmaxu[(q0 + tid) * 16 + blockIdx.x] = fmap(v);
    }
  } else {
    // ---- fully-unrolled loop with deferred hit masks (static indexing)
    unsigned hm[GNT];
    #pragma unroll
    for (int i = 0; i < GNT; ++i) hm[i] = 0u;
    #pragma unroll
    for (int t = 0; t < GNT; ++t) {
      unsigned short* Bc = (t & 1) ? Bs1 : Bs0;
      unsigned short* Bn = (t & 1) ? Bs0 : Bs1;
      if (t + 1 < GNT) {
        size_t gb = (size_t)(c0 + (t + 1) * GBC) * DK;
        #pragma unroll
        for (int i = 0; i < 4; ++i)
          gload16(&xbf[gb + soff[i]], &Bn[(tid + i * 512) * 8]);
      }
      short8 bfr[2][4];
      #pragma unroll
      for (int n = 0; n < 2; ++n) {
        int rb = 32 * wn + 16 * n + tq;
        #pragma unroll
        for (int ks = 0; ks < 4; ++ks)
          bfr[n][ks] = *(const short8*)&Bc[rb * DK +
                          (((ks*4+th) ^ (rb & 7)) * 8)];
      }
      f32x4 acc[4][2];
      #pragma unroll
      for (int m = 0; m < 4; ++m)
        #pragma unroll
        for (int n = 0; n < 2; ++n) {
          acc[m][n][0] = 0.f; acc[m][n][1] = 0.f;
          acc[m][n][2] = 0.f; acc[m][n][3] = 0.f;
        }
      #pragma unroll
      for (int ks = 0; ks < 4; ++ks) {
        short8 afq[4];
        #pragma unroll
        for (int m = 0; m < 4; ++m) {
          int ra = 64 * wm + 16 * m + tq;
          afq[m] = *(const short8*)&As[ra * DK +
                       (((ks*4+th) ^ (ra & 7)) * 8)];
        }
        #pragma unroll
        for (int m = 0; m < 4; ++m)
          #pragma unroll
          for (int n = 0; n < 2; ++n)
            acc[m][n] = __builtin_amdgcn_mfma_f32_16x16x32_bf16(
                afq[m], bfr[n][ks], acc[m][n], 0, 0, 0);
      }
      unsigned mm = 0;
      #pragma unroll
      for (int m = 0; m < 4; ++m)
        #pragma unroll
        for (int r = 0; r < 4; ++r)
          #pragma unroll
          for (int n = 0; n < 2; ++n)
            mm |= (acc[m][n][r] >= tauf[m][r])
                      ? (1u << ((m << 3) | (r << 1) | n)) : 0u;
      hm[t] = mm;
      __syncthreads();
    }
    // deferred candidate flush: atomics OUTSIDE the pipelined loop.
    // Same set as inline (same compares), order changes only.
    #pragma unroll
    for (int t = 0; t < GNT; ++t) {
      unsigned mm = hm[t];
      while (mm) {
        int b = __ffs(mm) - 1;
        mm &= mm - 1;
        int m = b >> 3, r = (b >> 1) & 3, n = b & 1;
        int row = q0 + 64*wm + 16*m + 4*th + r;
        int col = c0 + t * GBC + 32*wn + 16*n + tq;
        int slot = atomicAdd(&cnt[row], 1);
        if (slot < CAP) cand[(size_t)row * CAP + slot] = col;
      }
    }
  }
}

// ---------------- tau = min of 16 group maxes (<= true 16th value, provably);
// also zero candidate counters
__global__ __launch_bounds__(256) void k_tau(const unsigned* __restrict__ gmaxu,
    unsigned* __restrict__ tau_u, int* __restrict__ cnt) {
  int row = blockIdx.x * 256 + threadIdx.x;
  unsigned t = 0xFFFFFFFFu;
  #pragma unroll
  for (int g = 0; g < 16; ++g) t = min(t, gmaxu[row * 16 + g]);
  tau_u[row] = t;
  cnt[row] = 0;
}

// ---------------- TWO-PHASE exact rescore (used when workspace allows the
// +32 MB score buffer). Splits score (needs pre[8]/fmaf chains) from rank
// (needs sv/cc/rk arrays) so NEITHER kernel carries the union register set.
// Round-14 measured: both below the 195-us top-5 cutoff; total 668 us.
// PHASE A: one block per row, 512 threads, one candidate per thread.
// Dot = sequential fmaf chain (round-3-proven exact match vs the reference;
// summation order MUST NOT change). (512,4) caps VGPR at 128 (under cliff).
__global__ __launch_bounds__(512, 4) void k_score(const float* __restrict__ x,
    const int* __restrict__ cand, const int* __restrict__ cnt,
    float* __restrict__ svbuf) {
  __shared__ __align__(16) float arow[DK];
  int row = blockIdx.x;
  int i = threadIdx.x;
  int n = cnt[row];
  if (i < 32)
    *(f4*)&arow[i * 4] = *(const f4*)&x[(size_t)row * DK + i * 4];
  __syncthreads();
  if (n > CAP || i >= n) return;     // overflow rows: k_exact_of
  const f4* as = (const f4*)arow;
  int col = cand[(size_t)row * CAP + i];
  const f4* b4 = (const f4*)&x[(size_t)col * DK];
  f4 pre[8];
  #pragma unroll
  for (int q = 0; q < 8; ++q) pre[q] = b4[q * 4];     // one load per 64B line
  float t = 0.f;
  #pragma unroll
  for (int k = 0; k < 32; ++k) {
    f4 a = as[k];
    f4 b = ((k & 3) == 0) ? pre[k >> 2] : b4[k];      // static select (unroll)
    t = fmaf(a.x, b.x, t); t = fmaf(a.y, b.y, t);
    t = fmaf(a.z, b.z, t); t = fmaf(a.w, b.w, t);
  }
  svbuf[(size_t)row * CAP + i] = t;
}

// PHASE B: one wave per row; coalesced score/col loads; chunked broadcast
// rank with the SAME sentinels and (value desc, col asc) comparison as the
// proven combined kernel -> bitwise-identical idx. ~24-reg arrays + temps,
// under the 128 cliff, no spills.
__global__ __launch_bounds__(256) void k_rank(const float* __restrict__ svbuf,
    const int* __restrict__ cand, const int* __restrict__ cnt,
    int* __restrict__ idx) {
  int lane = threadIdx.x & 63, wid = threadIdx.x >> 6;
  int row = blockIdx.x * 4 + wid;
  int n = cnt[row];
  if (n > CAP) return;               // k_exact_of covers this row
  int NCH = (n + 63) >> 6;
  float sv[8]; int cc[8]; int rk[8];
  #pragma unroll
  for (int p = 0; p < 8; ++p) {
    sv[p] = -3.0e38f; cc[p] = 0x7fffffff; rk[p] = 0;
  }
  #pragma unroll
  for (int p = 0; p < 8; ++p) {
    if (p < NCH) {
      int i = p * 64 + lane;
      if (i < n) {
        sv[p] = svbuf[(size_t)row * CAP + i];
        cc[p] = cand[(size_t)row * CAP + i];
      }
    }
  }
  #pragma unroll
  for (int q = 0; q < 8; ++q) {
    if (q < NCH) {
      for (int l = 0; l < 64; ++l) {
        float vj = __shfl(sv[q], l, 64);
        int   cj = __shfl(cc[q], l, 64);
        #pragma unroll
        for (int p = 0; p < 8; ++p)
          rk[p] += (vj > sv[p] || (vj == sv[p] && cj < cc[p])) ? 1 : 0;
      }
    }
  }
  #pragma unroll
  for (int p = 0; p < 8; ++p) {
    int i = p * 64 + lane;
    if (p < NCH && i < n && rk[p] < TK) idx[(size_t)row * TK + rk[p]] = cc[p];
  }
}

// ---------------- exact fp32-chain rescore of candidates -> top-16 (TIER-2:
// used when workspace lacks the score buffer; round-13 measured 228 us).
__global__ __launch_bounds__(256, 4) void k_exact(const float* __restrict__ x,
    const int* __restrict__ cand, const int* __restrict__ cnt,
    int* __restrict__ idx) {
  __shared__ __align__(16) float arow[4][DK];
  int lane = threadIdx.x & 63, wid = threadIdx.x >> 6;
  int row = blockIdx.x * 4 + wid;
  int n = cnt[row];
  // stage this wave's query row into LDS (all later reads are broadcasts)
  if (lane < 32)
    *(f4*)&arow[wid][lane * 4] = *(const f4*)&x[(size_t)row * DK + lane * 4];
  __syncthreads();
  if (n > CAP) return;               // k_exact_of covers this row
  const f4* as = (const f4*)&arow[wid][0];

  if (n <= 64) {
    // ---- fast path: one candidate per lane
    bool ok = lane < n;
    int col = ok ? cand[(size_t)row * CAP + lane] : row;
    const f4* b4 = (const f4*)&x[(size_t)col * DK];
    f4 pre[8];
    #pragma unroll
    for (int q = 0; q < 8; ++q) pre[q] = b4[q * 4];   // one load per 64B line
    float t = 0.f;
    #pragma unroll
    for (int k = 0; k < 32; ++k) {
      f4 a = as[k];
      f4 b = ((k & 3) == 0) ? pre[k >> 2] : b4[k];    // static select (unroll)
      t = fmaf(a.x, b.x, t); t = fmaf(a.y, b.y, t);
      t = fmaf(a.z, b.z, t); t = fmaf(a.w, b.w, t);
    }
    float sv = ok ? t : -3.0e38f;
    int cc = ok ? col : 0x7fffffff;
    int rk = 0;
    for (int l = 0; l < 64; ++l) {
      float vj = __shfl(sv, l, 64);
      int   cj = __shfl(cc, l, 64);
      rk += (vj > sv || (vj == sv && cj < cc)) ? 1 : 0;
    }
    if (ok && rk < TK) idx[(size_t)row * TK + rk] = cc;
  } else {
    // ---- general path (64 < n <= CAP): chunked, same structure
    int NCH = (n + 63) >> 6;
    float sv[8]; int cc[8]; int rk[8];
    #pragma unroll
    for (int p = 0; p < 8; ++p) {
      sv[p] = -3.0e38f; cc[p] = 0x7fffffff; rk[p] = 0;
    }
    #pragma unroll
    for (int p = 0; p < 8; ++p) {
      if (p < NCH) {
        int i = p * 64 + lane;
        bool ok = i < n;
        int col = ok ? cand[(size_t)row * CAP + i] : row;
        const f4* b4 = (const f4*)&x[(size_t)col * DK];
        f4 pre[8];
        #pragma unroll
        for (int q = 0; q < 8; ++q) pre[q] = b4[q * 4];
        float t = 0.f;
        #pragma unroll
        for (int k = 0; k < 32; ++k) {
          f4 a = as[k];
          f4 b = ((k & 3) == 0) ? pre[k >> 2] : b4[k];
          t = fmaf(a.x, b.x, t); t = fmaf(a.y, b.y, t);
          t = fmaf(a.z, b.z, t); t = fmaf(a.w, b.w, t);
        }
        if (ok) { sv[p] = t; cc[p] = col; }
      }
    }
    #pragma unroll
    for (int q = 0; q < 8; ++q) {
      if (q < NCH) {
        for (int l = 0; l < 64; ++l) {
          float vj = __shfl(sv[q], l, 64);
          int   cj = __shfl(cc[q], l, 64);
          #pragma unroll
          for (int p = 0; p < 8; ++p)
            rk[p] += (vj > sv[p] || (vj == sv[p] && cj < cc[p])) ? 1 : 0;
        }
      }
    }
    #pragma unroll
    for (int p = 0; p < 8; ++p) {
      int i = p * 64 + lane;
      if (p < NCH && i < n && rk[p] < TK) idx[(size_t)row * TK + rk[p]] = cc[p];
    }
  }
}

// ---------------- overflow insurance: exact full-row scan for rows with
// cnt > CAP (statistically never taken; all blocks early-exit otherwise)
__global__ __launch_bounds__(256) void k_exact_of(const float* __restrict__ x,
    const int* __restrict__ cnt, int* __restrict__ idx) {
  int lane = threadIdx.x & 63, wid = threadIdx.x >> 6;
  int row = blockIdx.x * 4 + wid;
  if (cnt[row] <= CAP) return;
  const f4* a4 = (const f4*)&x[(size_t)row * DK];
  float bv[16]; int bc[16];
  #pragma unroll
  for (int i = 0; i < 16; ++i) { bv[i] = -3.0e38f; bc[i] = 0x7fffffff; }
  for (int c = lane; c < BN; c += 64) {
    const f4* b4 = (const f4*)&x[(size_t)c * DK];
    float s = 0.f;
    #pragma unroll
    for (int k = 0; k < 32; ++k) {
      f4 a = a4[k], b = b4[k];
      s = fmaf(a.x, b.x, s); s = fmaf(a.y, b.y, s);
      s = fmaf(a.z, b.z, s); s = fmaf(a.w, b.w, s);
    }
    if (s > bv[15] || (s == bv[15] && c < bc[15])) {
      bv[15] = s; bc[15] = c;
      #pragma unroll
      for (int i = 15; i > 0; --i) {
        bool sw = bv[i] > bv[i-1] || (bv[i] == bv[i-1] && bc[i] < bc[i-1]);
        if (sw) {
          float tv = bv[i]; bv[i] = bv[i-1]; bv[i-1] = tv;
          int tc = bc[i]; bc[i] = bc[i-1]; bc[i-1] = tc;
        }
      }
    }
  }
  for (int t = 0; t < TK; ++t) {
    float mv = bv[0]; int mc = bc[0];
    #pragma unroll
    for (int w = 1; w < 64; w <<= 1) {
      float ov = __shfl_xor(mv, w, 64);
      int   oc = __shfl_xor(mc, w, 64);
      if (ov > mv || (ov == mv && oc < mc)) { mv = ov; mc = oc; }
    }
    if (bv[0] == mv && bc[0] == mc) {
      idx[(size_t)row * TK + t] = mc;
      #pragma unroll
      for (int i = 0; i < 15; ++i) { bv[i] = bv[i+1]; bc[i] = bc[i+1]; }
      bv[15] = -3.0e38f; bc[15] = 0x7fffffff;
    }
  }
}

// ================= OLD fallback pipeline (round-3, passing) =================
__global__ __launch_bounds__(256) void k_sim(const float* __restrict__ x,
    int* __restrict__ candC) {
  __shared__ __align__(16) float At[DK][RPB];
  __shared__ __align__(16) float Bt[CT][DK];
  int tid = threadIdx.x;
  int rowblk = blockIdx.x & 255;
  int strip  = blockIdx.x >> 8;
  int r0 = rowblk * RPB;
  int tx = tid & 15, ty = tid >> 4;
  int lane = tid & 63;
  int gbase = lane & 48;
  for (int i = 0; i < 8; ++i) {
    int s = tid + i * 256;
    int r = s >> 5, kq = s & 31;
    f4 v = *(const f4*)&x[(size_t)(r0 + r) * DK + kq * 4];
    At[kq*4+0][r] = v.x; At[kq*4+1][r] = v.y;
    At[kq*4+2][r] = v.z; At[kq*4+3][r] = v.w;
  }
  float listV[4]; int listC[4];
  #pragma unroll
  for (int rr = 0; rr < 4; ++rr) { listV[rr] = -3.0e38f; listC[rr] = 0; }
  __syncthreads();
  for (int ct = 0; ct < SCOLS / CT; ++ct) {
    int c0 = strip * SCOLS + ct * CT;
    for (int i = 0; i < 8; ++i) {
      int s = tid + i * 256;
      int c = s >> 5, kq = s & 31;
      f4 v = *(const f4*)&x[(size_t)(c0 + c) * DK + kq * 4];
      ((f4*)&Bt[c][0])[kq ^ (c & 7)] = v;
    }
    __syncthreads();
    float acc[4][4];
    #pragma unroll
    for (int a = 0; a < 4; ++a)
      #pragma unroll
      for (int b = 0; b < 4; ++b) acc[a][b] = 0.f;
    #pragma unroll 2
    for (int k4 = 0; k4 < 32; ++k4) {
      float ta[4][4], tb[4][4];
      #pragma unroll
      for (int j = 0; j < 4; ++j)
        *(f4*)&ta[j][0] = *(const f4*)&At[k4*4 + j][ty*4];
      #pragma unroll
      for (int jj = 0; jj < 4; ++jj) {
        int c = tx + 16*jj;
        *(f4*)&tb[jj][0] = ((const f4*)&Bt[c][0])[k4 ^ (c & 7)];
      }
      #pragma unroll
      for (int rr = 0; rr < 4; ++rr)
        #pragma unroll
        for (int jj = 0; jj < 4; ++jj)
          acc[rr][jj] += ta[0][rr]*tb[jj][0] + ta[1][rr]*tb[jj][1]
                       + ta[2][rr]*tb[jj][2] + ta[3][rr]*tb[jj][3];
    }
    float tau[4];
    #pragma unroll
    for (int rr = 0; rr < 4; ++rr) tau[rr] = __shfl(listV[rr], 15, 16);
    #pragma unroll
    for (int rr = 0; rr < 4; ++rr) {
      #pragma unroll
      for (int jj = 0; jj < 4; ++jj) {
        float v = acc[rr][jj];
        unsigned long long bal = __ballot(v > tau[rr]);
        unsigned bits = (unsigned)((bal >> gbase) & 0xffffULL);
        while (bits) {
          int l = __ffs(bits) - 1;
          float vb = __shfl(v, l, 16);
          int colb = c0 + l + 16*jj;
          unsigned long long g2 = __ballot(listV[rr] > vb);
          int cnt2 = __popc((unsigned)((g2 >> gbase) & 0xffffULL));
          float sV = __shfl_up(listV[rr], 1, 16);
          int   sC = __shfl_up(listC[rr], 1, 16);
          if (tx == cnt2)      { listV[rr] = vb; listC[rr] = colb; }
          else if (tx > cnt2)  { listV[rr] = sV; listC[rr] = sC; }
          bits &= bits - 1;
        }
      }
    }
    __syncthreads();
  }
  #pragma unroll
  for (int rr = 0; rr < 4; ++rr) {
    int row = r0 + ty * 4 + rr;
    candC[row * (NSTRIP * TK) + strip * TK + tx] = listC[rr];
  }
}

__global__ __launch_bounds__(256) void k_rescore(const float* __restrict__ x,
    const int* __restrict__ candC, int* __restrict__ idx) {
  int lane = threadIdx.x & 63;
  int wid  = threadIdx.x >> 6;
  int half = lane >> 5;
  int ci   = lane & 31;
  int row  = (blockIdx.x * 4 + wid) * 2 + half;
  int col  = candC[row * (NSTRIP * TK) + ci];
  const f4* a4 = (const f4*)&x[(size_t)row * DK];
  const f4* b4 = (const f4*)&x[(size_t)col * DK];
  float s = 0.f;
  #pragma unroll
  for (int k = 0; k < 32; ++k) {
    f4 a = a4[k], b = b4[k];
    s = fmaf(a.x, b.x, s);
    s = fmaf(a.y, b.y, s);
    s = fmaf(a.z, b.z, s);
    s = fmaf(a.w, b.w, s);
  }
  int rank = 0;
  #pragma unroll
  for (int j = 0; j < 32; ++j) {
    float vj = __shfl(s, j, 32);
    int   cj = __shfl(col, j, 32);
    if (vj > s || (vj == s && cj < col)) rank++;
  }
  if (rank < TK) idx[row * TK + rank] = col;
}
// ================= end old fallback =================

// ---------------- CSR by dst: count, scan, fill
__global__ __launch_bounds__(256) void k_count(const int* __restrict__ idx,
                                               int* __restrict__ deg) {
  int i = blockIdx.x * 256 + threadIdx.x;
  int b = i >> 4;
  int t = idx[i];
  if (t != b) atomicAdd(&deg[t], 1);
}

__global__ __launch_bounds__(1024) void k_scan(const int* __restrict__ deg,
                                               int* __restrict__ off) {
  __shared__ int sdat[1024];
  int tid = threadIdx.x;
  int carry = 0;
  for (int ch = 0; ch < BN / 1024; ++ch) {
    int i = ch * 1024 + tid;
    int v = deg[i];
    sdat[tid] = v;
    __syncthreads();
    for (int o = 1; o < 1024; o <<= 1) {
      int t = (tid >= o) ? sdat[tid - o] : 0;
      __syncthreads();
      sdat[tid] += t;
      __syncthreads();
    }
    off[i] = sdat[tid] - v + carry;
    int tot = sdat[1023];
    __syncthreads();
    carry += tot;
  }
  if (tid == 0) off[BN] = carry;
}

__global__ __launch_bounds__(256) void k_fill(const int* __restrict__ idx,
    const int* __restrict__ off, int* __restrict__ cur, int* __restrict__ csr) {
  int i = blockIdx.x * 256 + threadIdx.x;
  if (i >= BN * (TK + 1)) return;
  int b = i / (TK + 1);
  int j = i - b * (TK + 1);
  int t;
  if (j < TK) { t = idx[b * TK + j]; if (t == b) return; }
  else t = b;
  int p = atomicAdd(&cur[t], 1);
  csr[off[t] + p] = b;
}

// ---------------- per-dst online segment softmax + aggregation
__global__ __launch_bounds__(256) void k_aggr(const float* __restrict__ xl,
    const float* __restrict__ xr, const float* __restrict__ att,
    const float* __restrict__ bias, const int* __restrict__ off,
    const int* __restrict__ csr, float* __restrict__ out) {
  int t = blockIdx.x;
  int tid = threadIdx.x;
  int o0 = off[t], o1 = off[t + 1];
  float xrv = xr[(size_t)t * HC + tid];
  float av = att[tid];
  float m = -3.0e38f, den = 0.f, acc = 0.f;
  for (int e = o0; e < o1; ++e) {
    int s = csr[e];
    float xlv = xl[(size_t)s * HC + tid];
    float z = xlv + xrv;
    z = (z > 0.f) ? z : 0.2f * z;
    float sc = z * av;
    #pragma unroll
    for (int w = 1; w < 64; w <<= 1) sc += __shfl_xor(sc, w, 64);
    if (sc > m) {
      float r = __expf(m - sc);
      den *= r; acc *= r; m = sc;
    }
    float p = __expf(sc - m);
    den += p;
    acc += p * xlv;
  }
  out[(size_t)t * HC + tid] = acc / den + bias[tid];
}

extern "C" void kernel_launch(void* const* d_in, const int* in_sizes, int n_in,
                              void* d_out, int out_size, void* d_ws, size_t ws_size,
                              hipStream_t stream) {
  const float* x   = (const float*)d_in[0];
  const float* Wl  = (const float*)d_in[1];
  const float* bl  = (const float*)d_in[2];
  const float* Wr  = (const float*)d_in[3];
  const float* br  = (const float*)d_in[4];
  const float* att = (const float*)d_in[5];
  const float* bias= (const float*)d_in[6];
  float* out = (float*)d_out;

  // ---- new-path workspace layout (~75 MB) + optional score buffer (32 MB)
  const size_t need =
      (size_t)BN*HC*4*2          // xl, xr
    + (size_t)BN*DK*2            // xbf
    + (size_t)BN*16*4            // gmaxu
    + (size_t)BN*4               // tau_u
    + (size_t)BN*4               // cnt
    + (size_t)BN*CAP*4           // cand
    + (size_t)BN*TK*4            // idx
    + (size_t)BN*4*3 + 64        // deg, cur, off(+1)
    + (size_t)BN*(TK+1)*4;       // csr
  const size_t need2 = need + (size_t)BN*CAP*4;   // + svbuf (two-phase exact)

  if (ws_size >= need) {
    char* p = (char*)d_ws;
    float* xl = (float*)p;                    p += (size_t)BN*HC*4;
    float* xr = (float*)p;                    p += (size_t)BN*HC*4;
    unsigned short* xbf = (unsigned short*)p; p += (size_t)BN*DK*2;
    unsigned* gmaxu = (unsigned*)p;           p += (size_t)BN*16*4;
    unsigned* tau_u = (unsigned*)p;           p += (size_t)BN*4;
    int* cnt = (int*)p;                       p += (size_t)BN*4;
    int* cand = (int*)p;                      p += (size_t)BN*CAP*4;
    int* idx = (int*)p;                       p += (size_t)BN*TK*4;
    int* deg = (int*)p;                       p += (size_t)BN*4;
    int* off = (int*)p;                       p += (size_t)(BN+1)*4 + 60;
    int* cur = (int*)p;                       p += (size_t)BN*4;
    int* csr = (int*)p;                       p += (size_t)BN*(TK+1)*4;
    float* svbuf = (float*)p;                 // valid only if ws_size >= need2

    hipLaunchKernelGGL(k_init, dim3(BN*16/256), dim3(256), 0, stream,
                       deg, cur, gmaxu);
    hipLaunchKernelGGL(k_lin,  dim3(BN/16),  dim3(256), 0, stream,
                       x, Wl, bl, Wr, br, xl, xr);
    hipLaunchKernelGGL(k_cvt,  dim3(BN*DK/(256*8)), dim3(256), 0, stream, x, xbf);
    hipLaunchKernelGGL((k_gemm_t<0>), dim3(GSPLIT, BN/128), dim3(512), 0, stream,
                       xbf, gmaxu, (const unsigned*)nullptr,
                       (int*)nullptr, (int*)nullptr);
    hipLaunchKernelGGL(k_tau,  dim3(BN/256), dim3(256), 0, stream,
                       gmaxu, tau_u, cnt);
    hipLaunchKernelGGL((k_gemm_t<1>), dim3(GSPLIT, BN/128), dim3(512), 0, stream,
                       xbf, (unsigned*)nullptr, tau_u, cnt, cand);
    if (ws_size >= need2) {
      // two-phase exact rescore (high-TLP score pass + light rank pass)
      hipLaunchKernelGGL(k_score, dim3(BN), dim3(512), 0, stream,
                         x, cand, cnt, svbuf);
      hipLaunchKernelGGL(k_rank,  dim3(BN/4), dim3(256), 0, stream,
                         svbuf, cand, cnt, idx);
    } else {
      // tier-2: round-13 measured combined kernel (228 us)
      hipLaunchKernelGGL(k_exact, dim3(BN/4), dim3(256), 0, stream,
                         x, cand, cnt, idx);
    }
    hipLaunchKernelGGL(k_exact_of, dim3(BN/4), dim3(256), 0, stream,
                       x, cnt, idx);
    hipLaunchKernelGGL(k_count, dim3(BN*TK/256), dim3(256), 0, stream, idx, deg);
    hipLaunchKernelGGL(k_scan,  dim3(1), dim3(1024), 0, stream, deg, off);
    hipLaunchKernelGGL(k_fill,  dim3((BN*(TK+1))/256), dim3(256), 0, stream,
                       idx, off, cur, csr);
    hipLaunchKernelGGL(k_aggr,  dim3(BN), dim3(256), 0, stream,
                       xl, xr, att, bias, off, csr, out);
  } else {
    // ---- fallback: round-3 passing pipeline (~40 MB)
    float* xl    = (float*)d_ws;
    float* xr    = xl + (size_t)BN * HC;
    int* candC   = (int*)(xr + (size_t)BN * HC);
    int* idx     = candC + (size_t)BN * NSTRIP * TK;
    int* deg     = idx + (size_t)BN * TK;
    int* off     = deg + BN;
    int* cur     = off + (BN + 1);
    int* csr     = cur + BN;
    unsigned* gmaxu_dummy = (unsigned*)(csr + (size_t)BN * (TK + 1));

    hipLaunchKernelGGL(k_init,  dim3(BN/256), dim3(256), 0, stream,
                       deg, cur, gmaxu_dummy);
    hipLaunchKernelGGL(k_lin,   dim3(BN/16),  dim3(256), 0, stream,
                       x, Wl, bl, Wr, br, xl, xr);
    hipLaunchKernelGGL(k_sim,   dim3(NSTRIP*(BN/RPB)), dim3(256), 0, stream,
                       x, candC);
    hipLaunchKernelGGL(k_rescore, dim3(BN/8), dim3(256), 0, stream,
                       x, candC, idx);
    hipLaunchKernelGGL(k_count, dim3(BN*TK/256), dim3(256), 0, stream, idx, deg);
    hipLaunchKernelGGL(k_scan,  dim3(1), dim3(1024), 0, stream, deg, off);
    hipLaunchKernelGGL(k_fill,  dim3((BN*(TK+1))/256), dim3(256), 0, stream,
                       idx, off, cur, csr);
    hipLaunchKernelGGL(k_aggr,  dim3(BN), dim3(256), 0, stream,
                       xl, xr, att, bias, off, csr, out);
  }
}

// Round 17
// 665.211 us; speedup vs baseline: 1.0082x; 1.0082x over previous
//
#include <hip/hip_runtime.h>
#include <math.h>

// Problem constants (fixed by the reference; k input is ignored, always 16)
#define BN 16384
#define DK 128
#define HN 4
#define CN 64
#define HC 256
#define TK 16
#define CAP 512              // candidate buffer capacity per row

// ---- streamed GEMM geometry: 128-row panel x 1024-col strip per block
#define GSPLIT 16            // column strips
#define GSPAN  1024          // cols per strip (= one gmax group)
#define GBC    128           // cols per B tile (32 KB)
#define GNT    (GSPAN / GBC) // 8 steps per strip

// ---- old fallback pipeline geometry
#define NSTRIP 2
#define SCOLS (BN / NSTRIP)
#define RPB 64
#define CT 64

typedef float4 f4;
typedef __attribute__((ext_vector_type(8))) short short8;
typedef __attribute__((ext_vector_type(4))) float f32x4;

__device__ __forceinline__ unsigned bf_rne(float f) {
  unsigned u = __float_as_uint(f);
  u += 0x7fffu + ((u >> 16) & 1u);
  return u >> 16;
}

// order-preserving float->uint map (monotone for all finite floats)
__device__ __forceinline__ unsigned fmap(float f) {
  unsigned b = __float_as_uint(f);
  return (b & 0x80000000u) ? ~b : (b | 0x80000000u);
}

// async global->LDS, 16B per lane (dest is wave-uniform base + lane*16)
__device__ __forceinline__ void gload16(const unsigned short* g,
                                        unsigned short* l) {
  __builtin_amdgcn_global_load_lds(
      (const __attribute__((address_space(1))) unsigned int*)g,
      (__attribute__((address_space(3))) unsigned int*)l, 16, 0, 0);
}

// ---------------- init: deg=1, cur=0, gmaxu=0 (re-init every call)
__global__ __launch_bounds__(256) void k_init(int* deg, int* cur,
                                              unsigned* gmaxu) {
  int i = blockIdx.x * 256 + threadIdx.x;
  if (i < BN) { deg[i] = 1; cur[i] = 0; }
  if (i < BN * 16) gmaxu[i] = 0u;    // mapped ~ -inf
}

// ---------------- x_l = x@W_l + b_l ; x_r = x@W_r + b_r  (fp32, 16 rows/block)
__global__ __launch_bounds__(256) void k_lin(const float* __restrict__ x,
    const float* __restrict__ Wl, const float* __restrict__ bl,
    const float* __restrict__ Wr, const float* __restrict__ br,
    float* __restrict__ xl, float* __restrict__ xr) {
  __shared__ __align__(16) float xst[DK][16];
  int tid = threadIdx.x;
  int r0 = blockIdx.x * 16;
  for (int i = 0; i < 2; ++i) {
    int s = tid + i * 256;
    int r = s >> 5, kq = s & 31;
    f4 v = *(const f4*)&x[(size_t)(r0 + r) * DK + kq * 4];
    xst[kq*4+0][r] = v.x; xst[kq*4+1][r] = v.y;
    xst[kq*4+2][r] = v.z; xst[kq*4+3][r] = v.w;
  }
  __syncthreads();
  float al[16], ar[16];
  #pragma unroll
  for (int r = 0; r < 16; ++r) { al[r] = 0.f; ar[r] = 0.f; }
  for (int k = 0; k < DK; ++k) {
    float wl = Wl[k * HC + tid];
    float wr = Wr[k * HC + tid];
    float xv[16];
    *(f4*)&xv[0]  = *(const f4*)&xst[k][0];
    *(f4*)&xv[4]  = *(const f4*)&xst[k][4];
    *(f4*)&xv[8]  = *(const f4*)&xst[k][8];
    *(f4*)&xv[12] = *(const f4*)&xst[k][12];
    #pragma unroll
    for (int r = 0; r < 16; ++r) { al[r] += xv[r] * wl; ar[r] += xv[r] * wr; }
  }
  float bbl = bl[tid], bbr = br[tid];
  #pragma unroll
  for (int r = 0; r < 16; ++r) {
    xl[(size_t)(r0 + r) * HC + tid] = al[r] + bbl;
    xr[(size_t)(r0 + r) * HC + tid] = ar[r] + bbr;
  }
}

// ---------------- x (fp32) -> x_bf (bf16, RNE)
__global__ __launch_bounds__(256) void k_cvt(const float* __restrict__ x,
                                             unsigned short* __restrict__ xbf) {
  size_t base = (size_t)(blockIdx.x * 256 + threadIdx.x) * 8;
  f4 a = *(const f4*)&x[base];
  f4 b = *(const f4*)&x[base + 4];
  uint4 o;
  o.x = bf_rne(a.x) | (bf_rne(a.y) << 16);
  o.y = bf_rne(a.z) | (bf_rne(a.w) << 16);
  o.z = bf_rne(b.x) | (bf_rne(b.y) << 16);
  o.w = bf_rne(b.z) | (bf_rne(b.w) << 16);
  *(uint4*)&xbf[base] = o;
}

// ---------------- streamed MFMA scorer: round-10 schedule. ROUND-17 CHANGE:
// B fragments also read per-ks (bfq[2], 8 regs) instead of hoisted bfr[2][4]
// (32 regs/step). Round-16 (afq change) halved scratch (WRITE 327->186 MB,
// FETCH 174->38 MB, dur 197->188); the remaining spill source is the hoisted
// B-fragments + unrolled addressing against the unified 256-reg VGPR+AGPR
// file (128 arch VGPR + 32 AGPR acc at 2 waves/SIMD). Per ks-slice now:
// read afq[4] + bfq[2], issue 8 MFMAs. LDS read COUNT unchanged (A:16, B:8
// ds_read_b128/step/wave), only re-scheduled. Live set ~90 VGPR + 32 AGPR ->
// no scratch. Scores bitwise identical: same LDS bytes, same ks-ascending
// MFMA chain per acc cell; both MODEs transformed identically.
// Per block: 128-row panel vs 1024-col strip, 8 steps of 128 cols, 8 waves
// (2x4 of 64x32 tiles). B tiles double-buffered with global_load_lds issued
// before compute, one __syncthreads per step.
// acc[m][n][r]: row = q0+64wm+16m+4th+r, col = c0+128t+32wn+16n+tq.
// MODE 0: runtime loop, lane-local running max, block-end reduce.
// MODE 1: fully-unrolled loop builds per-step 32-bit hit masks in
// statically-indexed registers; atomicAdd+store flush AFTER the loop.
template <int MODE>
__global__ __launch_bounds__(512, 1) void k_gemm_t(
    const unsigned short* __restrict__ xbf, unsigned* __restrict__ gmaxu,
    const unsigned* __restrict__ tau_u, int* __restrict__ cnt,
    int* __restrict__ cand) {
  __shared__ __align__(16) unsigned short As[128 * DK];
  __shared__ __align__(16) unsigned short Bs0[128 * DK];
  __shared__ __align__(16) unsigned short Bs1[128 * DK];
  __shared__ float red[4][128];
  int tid = threadIdx.x;
  int q0 = blockIdx.y * 128;
  int c0 = blockIdx.x * GSPAN;
  int lane = tid & 63;
  int wid = tid >> 6;
  int wm = wid & 1, wn = wid >> 1;
  int tq = lane & 15, th = lane >> 4;

  // t-invariant staging geometry: slot = tid + i*512 -> (row, 16B chunk)
  // source chunk pre-swizzled so linear LDS dest == XOR-swizzled layout
  int soff[4];       // element offset within a 128-row tile
  #pragma unroll
  for (int i = 0; i < 4; ++i) {
    int slot = tid + i * 512;
    int row = slot >> 4, c8 = slot & 15;
    soff[i] = row * DK + ((c8 ^ (row & 7)) * 8);
  }
  // prologue: stage A panel + B tile 0
  #pragma unroll
  for (int i = 0; i < 4; ++i)
    gload16(&xbf[(size_t)q0 * DK + soff[i]], &As[(tid + i * 512) * 8]);
  #pragma unroll
  for (int i = 0; i < 4; ++i)
    gload16(&xbf[(size_t)c0 * DK + soff[i]], &Bs0[(tid + i * 512) * 8]);
  __syncthreads();   // drains vmcnt -> A and B0 resident

  float gmx[4][4];   // MODE 0: lane-local running max
  float tauf[4][4];  // MODE 1: float-domain threshold
  if constexpr (MODE == 0) {
    #pragma unroll
    for (int m = 0; m < 4; ++m)
      #pragma unroll
      for (int r = 0; r < 4; ++r) gmx[m][r] = -3.0e38f;
  } else {
    #pragma unroll
    for (int m = 0; m < 4; ++m)
      #pragma unroll
      for (int r = 0; r < 4; ++r) {
        unsigned tu = tau_u[q0 + 64*wm + 16*m + 4*th + r];
        tauf[m][r] = __uint_as_float(
            (tu >= 0x80000000u) ? (tu ^ 0x80000000u) : ~tu);
      }
  }

  if constexpr (MODE == 0) {
    // ---- runtime loop (round-10 schedule; A+B frags re-read per ks)
    unsigned short* Bc = Bs0;
    unsigned short* Bn = Bs1;
    for (int t = 0; t < GNT; ++t) {
      if (t + 1 < GNT) {
        size_t gb = (size_t)(c0 + (t + 1) * GBC) * DK;
        #pragma unroll
        for (int i = 0; i < 4; ++i)
          gload16(&xbf[gb + soff[i]], &Bn[(tid + i * 512) * 8]);
      }
      f32x4 acc[4][2];
      #pragma unroll
      for (int m = 0; m < 4; ++m)
        #pragma unroll
        for (int n = 0; n < 2; ++n) {
          acc[m][n][0] = 0.f; acc[m][n][1] = 0.f;
          acc[m][n][2] = 0.f; acc[m][n][3] = 0.f;
        }
      #pragma unroll
      for (int ks = 0; ks < 4; ++ks) {
        short8 afq[4];
        #pragma unroll
        for (int m = 0; m < 4; ++m) {
          int ra = 64 * wm + 16 * m + tq;
          afq[m] = *(const short8*)&As[ra * DK +
                       (((ks*4+th) ^ (ra & 7)) * 8)];
        }
        short8 bfq[2];
        #pragma unroll
        for (int n = 0; n < 2; ++n) {
          int rb = 32 * wn + 16 * n + tq;
          bfq[n] = *(const short8*)&Bc[rb * DK +
                       (((ks*4+th) ^ (rb & 7)) * 8)];
        }
        #pragma unroll
        for (int m = 0; m < 4; ++m)
          #pragma unroll
          for (int n = 0; n < 2; ++n)
            acc[m][n] = __builtin_amdgcn_mfma_f32_16x16x32_bf16(
                afq[m], bfq[n], acc[m][n], 0, 0, 0);
      }
      #pragma unroll
      for (int m = 0; m < 4; ++m)
        #pragma unroll
        for (int r = 0; r < 4; ++r)
          gmx[m][r] = fmaxf(gmx[m][r], fmaxf(acc[m][0][r], acc[m][1][r]));
      __syncthreads();
      unsigned short* tb = Bc; Bc = Bn; Bn = tb;
    }
    // reduce over tq lanes, then across wn waves via LDS; plain store
    #pragma unroll
    for (int m = 0; m < 4; ++m)
      #pragma unroll
      for (int r = 0; r < 4; ++r) {
        float v = gmx[m][r];
        #pragma unroll
        for (int w = 1; w < 16; w <<= 1) v = fmaxf(v, __shfl_xor(v, w, 64));
        if (tq == 0) red[wn][64*wm + 16*m + 4*th + r] = v;
      }
    __syncthreads();
    if (tid < 128) {
      float v = fmaxf(fmaxf(red[0][tid], red[1][tid]),
                      fmaxf(red[2][tid], red[3][tid]));
      gmaxu[(q0 + tid) * 16 + blockIdx.x] = fmap(v);
    }
  } else {
    // ---- fully-unrolled loop with deferred hit masks (static indexing)
    unsigned hm[GNT];
    #pragma unroll
    for (int i = 0; i < GNT; ++i) hm[i] = 0u;
    #pragma unroll
    for (int t = 0; t < GNT; ++t) {
      unsigned short* Bc = (t & 1) ? Bs1 : Bs0;
      unsigned short* Bn = (t & 1) ? Bs0 : Bs1;
      if (t + 1 < GNT) {
        size_t gb = (size_t)(c0 + (t + 1) * GBC) * DK;
        #pragma unroll
        for (int i = 0; i < 4; ++i)
          gload16(&xbf[gb + soff[i]], &Bn[(tid + i * 512) * 8]);
      }
      f32x4 acc[4][2];
      #pragma unroll
      for (int m = 0; m < 4; ++m)
        #pragma unroll
        for (int n = 0; n < 2; ++n) {
          acc[m][n][0] = 0.f; acc[m][n][1] = 0.f;
          acc[m][n][2] = 0.f; acc[m][n][3] = 0.f;
        }
      #pragma unroll
      for (int ks = 0; ks < 4; ++ks) {
        short8 afq[4];
        #pragma unroll
        for (int m = 0; m < 4; ++m) {
          int ra = 64 * wm + 16 * m + tq;
          afq[m] = *(const short8*)&As[ra * DK +
                       (((ks*4+th) ^ (ra & 7)) * 8)];
        }
        short8 bfq[2];
        #pragma unroll
        for (int n = 0; n < 2; ++n) {
          int rb = 32 * wn + 16 * n + tq;
          bfq[n] = *(const short8*)&Bc[rb * DK +
                       (((ks*4+th) ^ (rb & 7)) * 8)];
        }
        #pragma unroll
        for (int m = 0; m < 4; ++m)
          #pragma unroll
          for (int n = 0; n < 2; ++n)
            acc[m][n] = __builtin_amdgcn_mfma_f32_16x16x32_bf16(
                afq[m], bfq[n], acc[m][n], 0, 0, 0);
      }
      unsigned mm = 0;
      #pragma unroll
      for (int m = 0; m < 4; ++m)
        #pragma unroll
        for (int r = 0; r < 4; ++r)
          #pragma unroll
          for (int n = 0; n < 2; ++n)
            mm |= (acc[m][n][r] >= tauf[m][r])
                      ? (1u << ((m << 3) | (r << 1) | n)) : 0u;
      hm[t] = mm;
      __syncthreads();
    }
    // deferred candidate flush: atomics OUTSIDE the pipelined loop.
    // Same set as inline (same compares), order changes only.
    #pragma unroll
    for (int t = 0; t < GNT; ++t) {
      unsigned mm = hm[t];
      while (mm) {
        int b = __ffs(mm) - 1;
        mm &= mm - 1;
        int m = b >> 3, r = (b >> 1) & 3, n = b & 1;
        int row = q0 + 64*wm + 16*m + 4*th + r;
        int col = c0 + t * GBC + 32*wn + 16*n + tq;
        int slot = atomicAdd(&cnt[row], 1);
        if (slot < CAP) cand[(size_t)row * CAP + slot] = col;
      }
    }
  }
}

// ---------------- tau = min of 16 group maxes (<= true 16th value, provably);
// also zero candidate counters
__global__ __launch_bounds__(256) void k_tau(const unsigned* __restrict__ gmaxu,
    unsigned* __restrict__ tau_u, int* __restrict__ cnt) {
  int row = blockIdx.x * 256 + threadIdx.x;
  unsigned t = 0xFFFFFFFFu;
  #pragma unroll
  for (int g = 0; g < 16; ++g) t = min(t, gmaxu[row * 16 + g]);
  tau_u[row] = t;
  cnt[row] = 0;
}

// ---------------- TWO-PHASE exact rescore (used when workspace allows the
// +32 MB score buffer). Splits score (needs pre[8]/fmaf chains) from rank
// (needs sv/cc/rk arrays) so NEITHER kernel carries the union register set.
// Round-14 measured: both below the 195-us top-5 cutoff; total 668 us.
// PHASE A: one block per row, 512 threads, one candidate per thread.
// Dot = sequential fmaf chain (round-3-proven exact match vs the reference;
// summation order MUST NOT change). (512,4) caps VGPR at 128 (under cliff).
__global__ __launch_bounds__(512, 4) void k_score(const float* __restrict__ x,
    const int* __restrict__ cand, const int* __restrict__ cnt,
    float* __restrict__ svbuf) {
  __shared__ __align__(16) float arow[DK];
  int row = blockIdx.x;
  int i = threadIdx.x;
  int n = cnt[row];
  if (i < 32)
    *(f4*)&arow[i * 4] = *(const f4*)&x[(size_t)row * DK + i * 4];
  __syncthreads();
  if (n > CAP || i >= n) return;     // overflow rows: k_exact_of
  const f4* as = (const f4*)arow;
  int col = cand[(size_t)row * CAP + i];
  const f4* b4 = (const f4*)&x[(size_t)col * DK];
  f4 pre[8];
  #pragma unroll
  for (int q = 0; q < 8; ++q) pre[q] = b4[q * 4];     // one load per 64B line
  float t = 0.f;
  #pragma unroll
  for (int k = 0; k < 32; ++k) {
    f4 a = as[k];
    f4 b = ((k & 3) == 0) ? pre[k >> 2] : b4[k];      // static select (unroll)
    t = fmaf(a.x, b.x, t); t = fmaf(a.y, b.y, t);
    t = fmaf(a.z, b.z, t); t = fmaf(a.w, b.w, t);
  }
  svbuf[(size_t)row * CAP + i] = t;
}

// PHASE B: one wave per row; coalesced score/col loads; chunked broadcast
// rank with the SAME sentinels and (value desc, col asc) comparison as the
// proven combined kernel -> bitwise-identical idx. ~24-reg arrays + temps,
// under the 128 cliff, no spills.
__global__ __launch_bounds__(256) void k_rank(const float* __restrict__ svbuf,
    const int* __restrict__ cand, const int* __restrict__ cnt,
    int* __restrict__ idx) {
  int lane = threadIdx.x & 63, wid = threadIdx.x >> 6;
  int row = blockIdx.x * 4 + wid;
  int n = cnt[row];
  if (n > CAP) return;               // k_exact_of covers this row
  int NCH = (n + 63) >> 6;
  float sv[8]; int cc[8]; int rk[8];
  #pragma unroll
  for (int p = 0; p < 8; ++p) {
    sv[p] = -3.0e38f; cc[p] = 0x7fffffff; rk[p] = 0;
  }
  #pragma unroll
  for (int p = 0; p < 8; ++p) {
    if (p < NCH) {
      int i = p * 64 + lane;
      if (i < n) {
        sv[p] = svbuf[(size_t)row * CAP + i];
        cc[p] = cand[(size_t)row * CAP + i];
      }
    }
  }
  #pragma unroll
  for (int q = 0; q < 8; ++q) {
    if (q < NCH) {
      for (int l = 0; l < 64; ++l) {
        float vj = __shfl(sv[q], l, 64);
        int   cj = __shfl(cc[q], l, 64);
        #pragma unroll
        for (int p = 0; p < 8; ++p)
          rk[p] += (vj > sv[p] || (vj == sv[p] && cj < cc[p])) ? 1 : 0;
      }
    }
  }
  #pragma unroll
  for (int p = 0; p < 8; ++p) {
    int i = p * 64 + lane;
    if (p < NCH && i < n && rk[p] < TK) idx[(size_t)row * TK + rk[p]] = cc[p];
  }
}

// ---------------- exact fp32-chain rescore of candidates -> top-16 (TIER-2:
// used when workspace lacks the score buffer; round-13 measured 228 us).
__global__ __launch_bounds__(256, 4) void k_exact(const float* __restrict__ x,
    const int* __restrict__ cand, const int* __restrict__ cnt,
    int* __restrict__ idx) {
  __shared__ __align__(16) float arow[4][DK];
  int lane = threadIdx.x & 63, wid = threadIdx.x >> 6;
  int row = blockIdx.x * 4 + wid;
  int n = cnt[row];
  // stage this wave's query row into LDS (all later reads are broadcasts)
  if (lane < 32)
    *(f4*)&arow[wid][lane * 4] = *(const f4*)&x[(size_t)row * DK + lane * 4];
  __syncthreads();
  if (n > CAP) return;               // k_exact_of covers this row
  const f4* as = (const f4*)&arow[wid][0];

  if (n <= 64) {
    // ---- fast path: one candidate per lane
    bool ok = lane < n;
    int col = ok ? cand[(size_t)row * CAP + lane] : row;
    const f4* b4 = (const f4*)&x[(size_t)col * DK];
    f4 pre[8];
    #pragma unroll
    for (int q = 0; q < 8; ++q) pre[q] = b4[q * 4];   // one load per 64B line
    float t = 0.f;
    #pragma unroll
    for (int k = 0; k < 32; ++k) {
      f4 a = as[k];
      f4 b = ((k & 3) == 0) ? pre[k >> 2] : b4[k];    // static select (unroll)
      t = fmaf(a.x, b.x, t); t = fmaf(a.y, b.y, t);
      t = fmaf(a.z, b.z, t); t = fmaf(a.w, b.w, t);
    }
    float sv = ok ? t : -3.0e38f;
    int cc = ok ? col : 0x7fffffff;
    int rk = 0;
    for (int l = 0; l < 64; ++l) {
      float vj = __shfl(sv, l, 64);
      int   cj = __shfl(cc, l, 64);
      rk += (vj > sv || (vj == sv && cj < cc)) ? 1 : 0;
    }
    if (ok && rk < TK) idx[(size_t)row * TK + rk] = cc;
  } else {
    // ---- general path (64 < n <= CAP): chunked, same structure
    int NCH = (n + 63) >> 6;
    float sv[8]; int cc[8]; int rk[8];
    #pragma unroll
    for (int p = 0; p < 8; ++p) {
      sv[p] = -3.0e38f; cc[p] = 0x7fffffff; rk[p] = 0;
    }
    #pragma unroll
    for (int p = 0; p < 8; ++p) {
      if (p < NCH) {
        int i = p * 64 + lane;
        bool ok = i < n;
        int col = ok ? cand[(size_t)row * CAP + i] : row;
        const f4* b4 = (const f4*)&x[(size_t)col * DK];
        f4 pre[8];
        #pragma unroll
        for (int q = 0; q < 8; ++q) pre[q] = b4[q * 4];
        float t = 0.f;
        #pragma unroll
        for (int k = 0; k < 32; ++k) {
          f4 a = as[k];
          f4 b = ((k & 3) == 0) ? pre[k >> 2] : b4[k];
          t = fmaf(a.x, b.x, t); t = fmaf(a.y, b.y, t);
          t = fmaf(a.z, b.z, t); t = fmaf(a.w, b.w, t);
        }
        if (ok) { sv[p] = t; cc[p] = col; }
      }
    }
    #pragma unroll
    for (int q = 0; q < 8; ++q) {
      if (q < NCH) {
        for (int l = 0; l < 64; ++l) {
          float vj = __shfl(sv[q], l, 64);
          int   cj = __shfl(cc[q], l, 64);
          #pragma unroll
          for (int p = 0; p < 8; ++p)
            rk[p] += (vj > sv[p] || (vj == sv[p] && cj < cc[p])) ? 1 : 0;
        }
      }
    }
    #pragma unroll
    for (int p = 0; p < 8; ++p) {
      int i = p * 64 + lane;
      if (p < NCH && i < n && rk[p] < TK) idx[(size_t)row * TK + rk[p]] = cc[p];
    }
  }
}

// ---------------- overflow insurance: exact full-row scan for rows with
// cnt > CAP (statistically never taken; all blocks early-exit otherwise)
__global__ __launch_bounds__(256) void k_exact_of(const float* __restrict__ x,
    const int* __restrict__ cnt, int* __restrict__ idx) {
  int lane = threadIdx.x & 63, wid = threadIdx.x >> 6;
  int row = blockIdx.x * 4 + wid;
  if (cnt[row] <= CAP) return;
  const f4* a4 = (const f4*)&x[(size_t)row * DK];
  float bv[16]; int bc[16];
  #pragma unroll
  for (int i = 0; i < 16; ++i) { bv[i] = -3.0e38f; bc[i] = 0x7fffffff; }
  for (int c = lane; c < BN; c += 64) {
    const f4* b4 = (const f4*)&x[(size_t)c * DK];
    float s = 0.f;
    #pragma unroll
    for (int k = 0; k < 32; ++k) {
      f4 a = a4[k], b = b4[k];
      s = fmaf(a.x, b.x, s); s = fmaf(a.y, b.y, s);
      s = fmaf(a.z, b.z, s); s = fmaf(a.w, b.w, s);
    }
    if (s > bv[15] || (s == bv[15] && c < bc[15])) {
      bv[15] = s; bc[15] = c;
      #pragma unroll
      for (int i = 15; i > 0; --i) {
        bool sw = bv[i] > bv[i-1] || (bv[i] == bv[i-1] && bc[i] < bc[i-1]);
        if (sw) {
          float tv = bv[i]; bv[i] = bv[i-1]; bv[i-1] = tv;
          int tc = bc[i]; bc[i] = bc[i-1]; bc[i-1] = tc;
        }
      }
    }
  }
  for (int t = 0; t < TK; ++t) {
    float mv = bv[0]; int mc = bc[0];
    #pragma unroll
    for (int w = 1; w < 64; w <<= 1) {
      float ov = __shfl_xor(mv, w, 64);
      int   oc = __shfl_xor(mc, w, 64);
      if (ov > mv || (ov == mv && oc < mc)) { mv = ov; mc = oc; }
    }
    if (bv[0] == mv && bc[0] == mc) {
      idx[(size_t)row * TK + t] = mc;
      #pragma unroll
      for (int i = 0; i < 15; ++i) { bv[i] = bv[i+1]; bc[i] = bc[i+1]; }
      bv[15] = -3.0e38f; bc[15] = 0x7fffffff;
    }
  }
}

// ================= OLD fallback pipeline (round-3, passing) =================
__global__ __launch_bounds__(256) void k_sim(const float* __restrict__ x,
    int* __restrict__ candC) {
  __shared__ __align__(16) float At[DK][RPB];
  __shared__ __align__(16) float Bt[CT][DK];
  int tid = threadIdx.x;
  int rowblk = blockIdx.x & 255;
  int strip  = blockIdx.x >> 8;
  int r0 = rowblk * RPB;
  int tx = tid & 15, ty = tid >> 4;
  int lane = tid & 63;
  int gbase = lane & 48;
  for (int i = 0; i < 8; ++i) {
    int s = tid + i * 256;
    int r = s >> 5, kq = s & 31;
    f4 v = *(const f4*)&x[(size_t)(r0 + r) * DK + kq * 4];
    At[kq*4+0][r] = v.x; At[kq*4+1][r] = v.y;
    At[kq*4+2][r] = v.z; At[kq*4+3][r] = v.w;
  }
  float listV[4]; int listC[4];
  #pragma unroll
  for (int rr = 0; rr < 4; ++rr) { listV[rr] = -3.0e38f; listC[rr] = 0; }
  __syncthreads();
  for (int ct = 0; ct < SCOLS / CT; ++ct) {
    int c0 = strip * SCOLS + ct * CT;
    for (int i = 0; i < 8; ++i) {
      int s = tid + i * 256;
      int c = s >> 5, kq = s & 31;
      f4 v = *(const f4*)&x[(size_t)(c0 + c) * DK + kq * 4];
      ((f4*)&Bt[c][0])[kq ^ (c & 7)] = v;
    }
    __syncthreads();
    float acc[4][4];
    #pragma unroll
    for (int a = 0; a < 4; ++a)
      #pragma unroll
      for (int b = 0; b < 4; ++b) acc[a][b] = 0.f;
    #pragma unroll 2
    for (int k4 = 0; k4 < 32; ++k4) {
      float ta[4][4], tb[4][4];
      #pragma unroll
      for (int j = 0; j < 4; ++j)
        *(f4*)&ta[j][0] = *(const f4*)&At[k4*4 + j][ty*4];
      #pragma unroll
      for (int jj = 0; jj < 4; ++jj) {
        int c = tx + 16*jj;
        *(f4*)&tb[jj][0] = ((const f4*)&Bt[c][0])[k4 ^ (c & 7)];
      }
      #pragma unroll
      for (int rr = 0; rr < 4; ++rr)
        #pragma unroll
        for (int jj = 0; jj < 4; ++jj)
          acc[rr][jj] += ta[0][rr]*tb[jj][0] + ta[1][rr]*tb[jj][1]
                       + ta[2][rr]*tb[jj][2] + ta[3][rr]*tb[jj][3];
    }
    float tau[4];
    #pragma unroll
    for (int rr = 0; rr < 4; ++rr) tau[rr] = __shfl(listV[rr], 15, 16);
    #pragma unroll
    for (int rr = 0; rr < 4; ++rr) {
      #pragma unroll
      for (int jj = 0; jj < 4; ++jj) {
        float v = acc[rr][jj];
        unsigned long long bal = __ballot(v > tau[rr]);
        unsigned bits = (unsigned)((bal >> gbase) & 0xffffULL);
        while (bits) {
          int l = __ffs(bits) - 1;
          float vb = __shfl(v, l, 16);
          int colb = c0 + l + 16*jj;
          unsigned long long g2 = __ballot(listV[rr] > vb);
          int cnt2 = __popc((unsigned)((g2 >> gbase) & 0xffffULL));
          float sV = __shfl_up(listV[rr], 1, 16);
          int   sC = __shfl_up(listC[rr], 1, 16);
          if (tx == cnt2)      { listV[rr] = vb; listC[rr] = colb; }
          else if (tx > cnt2)  { listV[rr] = sV; listC[rr] = sC; }
          bits &= bits - 1;
        }
      }
    }
    __syncthreads();
  }
  #pragma unroll
  for (int rr = 0; rr < 4; ++rr) {
    int row = r0 + ty * 4 + rr;
    candC[row * (NSTRIP * TK) + strip * TK + tx] = listC[rr];
  }
}

__global__ __launch_bounds__(256) void k_rescore(const float* __restrict__ x,
    const int* __restrict__ candC, int* __restrict__ idx) {
  int lane = threadIdx.x & 63;
  int wid  = threadIdx.x >> 6;
  int half = lane >> 5;
  int ci   = lane & 31;
  int row  = (blockIdx.x * 4 + wid) * 2 + half;
  int col  = candC[row * (NSTRIP * TK) + ci];
  const f4* a4 = (const f4*)&x[(size_t)row * DK];
  const f4* b4 = (const f4*)&x[(size_t)col * DK];
  float s = 0.f;
  #pragma unroll
  for (int k = 0; k < 32; ++k) {
    f4 a = a4[k], b = b4[k];
    s = fmaf(a.x, b.x, s);
    s = fmaf(a.y, b.y, s);
    s = fmaf(a.z, b.z, s);
    s = fmaf(a.w, b.w, s);
  }
  int rank = 0;
  #pragma unroll
  for (int j = 0; j < 32; ++j) {
    float vj = __shfl(s, j, 32);
    int   cj = __shfl(col, j, 32);
    if (vj > s || (vj == s && cj < col)) rank++;
  }
  if (rank < TK) idx[row * TK + rank] = col;
}
// ================= end old fallback =================

// ---------------- CSR by dst: count, scan, fill
__global__ __launch_bounds__(256) void k_count(const int* __restrict__ idx,
                                               int* __restrict__ deg) {
  int i = blockIdx.x * 256 + threadIdx.x;
  int b = i >> 4;
  int t = idx[i];
  if (t != b) atomicAdd(&deg[t], 1);
}

__global__ __launch_bounds__(1024) void k_scan(const int* __restrict__ deg,
                                               int* __restrict__ off) {
  __shared__ int sdat[1024];
  int tid = threadIdx.x;
  int carry = 0;
  for (int ch = 0; ch < BN / 1024; ++ch) {
    int i = ch * 1024 + tid;
    int v = deg[i];
    sdat[tid] = v;
    __syncthreads();
    for (int o = 1; o < 1024; o <<= 1) {
      int t = (tid >= o) ? sdat[tid - o] : 0;
      __syncthreads();
      sdat[tid] += t;
      __syncthreads();
    }
    off[i] = sdat[tid] - v + carry;
    int tot = sdat[1023];
    __syncthreads();
    carry += tot;
  }
  if (tid == 0) off[BN] = carry;
}

__global__ __launch_bounds__(256) void k_fill(const int* __restrict__ idx,
    const int* __restrict__ off, int* __restrict__ cur, int* __restrict__ csr) {
  int i = blockIdx.x * 256 + threadIdx.x;
  if (i >= BN * (TK + 1)) return;
  int b = i / (TK + 1);
  int j = i - b * (TK + 1);
  int t;
  if (j < TK) { t = idx[b * TK + j]; if (t == b) return; }
  else t = b;
  int p = atomicAdd(&cur[t], 1);
  csr[off[t] + p] = b;
}

// ---------------- per-dst online segment softmax + aggregation
__global__ __launch_bounds__(256) void k_aggr(const float* __restrict__ xl,
    const float* __restrict__ xr, const float* __restrict__ att,
    const float* __restrict__ bias, const int* __restrict__ off,
    const int* __restrict__ csr, float* __restrict__ out) {
  int t = blockIdx.x;
  int tid = threadIdx.x;
  int o0 = off[t], o1 = off[t + 1];
  float xrv = xr[(size_t)t * HC + tid];
  float av = att[tid];
  float m = -3.0e38f, den = 0.f, acc = 0.f;
  for (int e = o0; e < o1; ++e) {
    int s = csr[e];
    float xlv = xl[(size_t)s * HC + tid];
    float z = xlv + xrv;
    z = (z > 0.f) ? z : 0.2f * z;
    float sc = z * av;
    #pragma unroll
    for (int w = 1; w < 64; w <<= 1) sc += __shfl_xor(sc, w, 64);
    if (sc > m) {
      float r = __expf(m - sc);
      den *= r; acc *= r; m = sc;
    }
    float p = __expf(sc - m);
    den += p;
    acc += p * xlv;
  }
  out[(size_t)t * HC + tid] = acc / den + bias[tid];
}

extern "C" void kernel_launch(void* const* d_in, const int* in_sizes, int n_in,
                              void* d_out, int out_size, void* d_ws, size_t ws_size,
                              hipStream_t stream) {
  const float* x   = (const float*)d_in[0];
  const float* Wl  = (const float*)d_in[1];
  const float* bl  = (const float*)d_in[2];
  const float* Wr  = (const float*)d_in[3];
  const float* br  = (const float*)d_in[4];
  const float* att = (const float*)d_in[5];
  const float* bias= (const float*)d_in[6];
  float* out = (float*)d_out;

  // ---- new-path workspace layout (~75 MB) + optional score buffer (32 MB)
  const size_t need =
      (size_t)BN*HC*4*2          // xl, xr
    + (size_t)BN*DK*2            // xbf
    + (size_t)BN*16*4            // gmaxu
    + (size_t)BN*4               // tau_u
    + (size_t)BN*4               // cnt
    + (size_t)BN*CAP*4           // cand
    + (size_t)BN*TK*4            // idx
    + (size_t)BN*4*3 + 64        // deg, cur, off(+1)
    + (size_t)BN*(TK+1)*4;       // csr
  const size_t need2 = need + (size_t)BN*CAP*4;   // + svbuf (two-phase exact)

  if (ws_size >= need) {
    char* p = (char*)d_ws;
    float* xl = (float*)p;                    p += (size_t)BN*HC*4;
    float* xr = (float*)p;                    p += (size_t)BN*HC*4;
    unsigned short* xbf = (unsigned short*)p; p += (size_t)BN*DK*2;
    unsigned* gmaxu = (unsigned*)p;           p += (size_t)BN*16*4;
    unsigned* tau_u = (unsigned*)p;           p += (size_t)BN*4;
    int* cnt = (int*)p;                       p += (size_t)BN*4;
    int* cand = (int*)p;                      p += (size_t)BN*CAP*4;
    int* idx = (int*)p;                       p += (size_t)BN*TK*4;
    int* deg = (int*)p;                       p += (size_t)BN*4;
    int* off = (int*)p;                       p += (size_t)(BN+1)*4 + 60;
    int* cur = (int*)p;                       p += (size_t)BN*4;
    int* csr = (int*)p;                       p += (size_t)BN*(TK+1)*4;
    float* svbuf = (float*)p;                 // valid only if ws_size >= need2

    hipLaunchKernelGGL(k_init, dim3(BN*16/256), dim3(256), 0, stream,
                       deg, cur, gmaxu);
    hipLaunchKernelGGL(k_lin,  dim3(BN/16),  dim3(256), 0, stream,
                       x, Wl, bl, Wr, br, xl, xr);
    hipLaunchKernelGGL(k_cvt,  dim3(BN*DK/(256*8)), dim3(256), 0, stream, x, xbf);
    hipLaunchKernelGGL((k_gemm_t<0>), dim3(GSPLIT, BN/128), dim3(512), 0, stream,
                       xbf, gmaxu, (const unsigned*)nullptr,
                       (int*)nullptr, (int*)nullptr);
    hipLaunchKernelGGL(k_tau,  dim3(BN/256), dim3(256), 0, stream,
                       gmaxu, tau_u, cnt);
    hipLaunchKernelGGL((k_gemm_t<1>), dim3(GSPLIT, BN/128), dim3(512), 0, stream,
                       xbf, (unsigned*)nullptr, tau_u, cnt, cand);
    if (ws_size >= need2) {
      // two-phase exact rescore (high-TLP score pass + light rank pass)
      hipLaunchKernelGGL(k_score, dim3(BN), dim3(512), 0, stream,
                         x, cand, cnt, svbuf);
      hipLaunchKernelGGL(k_rank,  dim3(BN/4), dim3(256), 0, stream,
                         svbuf, cand, cnt, idx);
    } else {
      // tier-2: round-13 measured combined kernel (228 us)
      hipLaunchKernelGGL(k_exact, dim3(BN/4), dim3(256), 0, stream,
                         x, cand, cnt, idx);
    }
    hipLaunchKernelGGL(k_exact_of, dim3(BN/4), dim3(256), 0, stream,
                       x, cnt, idx);
    hipLaunchKernelGGL(k_count, dim3(BN*TK/256), dim3(256), 0, stream, idx, deg);
    hipLaunchKernelGGL(k_scan,  dim3(1), dim3(1024), 0, stream, deg, off);
    hipLaunchKernelGGL(k_fill,  dim3((BN*(TK+1))/256), dim3(256), 0, stream,
                       idx, off, cur, csr);
    hipLaunchKernelGGL(k_aggr,  dim3(BN), dim3(256), 0, stream,
                       xl, xr, att, bias, off, csr, out);
  } else {
    // ---- fallback: round-3 passing pipeline (~40 MB)
    float* xl    = (float*)d_ws;
    float* xr    = xl + (size_t)BN * HC;
    int* candC   = (int*)(xr + (size_t)BN * HC);
    int* idx     = candC + (size_t)BN * NSTRIP * TK;
    int* deg     = idx + (size_t)BN * TK;
    int* off     = deg + BN;
    int* cur     = off + (BN + 1);
    int* csr     = cur + BN;
    unsigned* gmaxu_dummy = (unsigned*)(csr + (size_t)BN * (TK + 1));

    hipLaunchKernelGGL(k_init,  dim3(BN/256), dim3(256), 0, stream,
                       deg, cur, gmaxu_dummy);
    hipLaunchKernelGGL(k_lin,   dim3(BN/16),  dim3(256), 0, stream,
                       x, Wl, bl, Wr, br, xl, xr);
    hipLaunchKernelGGL(k_sim,   dim3(NSTRIP*(BN/RPB)), dim3(256), 0, stream,
                       x, candC);
    hipLaunchKernelGGL(k_rescore, dim3(BN/8), dim3(256), 0, stream,
                       x, candC, idx);
    hipLaunchKernelGGL(k_count, dim3(BN*TK/256), dim3(256), 0, stream, idx, deg);
    hipLaunchKernelGGL(k_scan,  dim3(1), dim3(1024), 0, stream, deg, off);
    hipLaunchKernelGGL(k_fill,  dim3((BN*(TK+1))/256), dim3(256), 0, stream,
                       idx, off, cur, csr);
    hipLaunchKernelGGL(k_aggr,  dim3(BN), dim3(256), 0, stream,
                       xl, xr, att, bias, off, csr, out);
  }
}

// Round 18
// 663.116 us; speedup vs baseline: 1.0114x; 1.0032x over previous
//
#include <hip/hip_runtime.h>
#include <math.h>

// Problem constants (fixed by the reference; k input is ignored, always 16)
#define BN 16384
#define DK 128
#define HN 4
#define CN 64
#define HC 256
#define TK 16
#define CAP 512              // candidate buffer capacity per row

// ---- streamed GEMM geometry: 128-row panel x 1024-col strip per block
#define GSPLIT 16            // column strips
#define GSPAN  1024          // cols per strip (= one gmax group)
#define GBC    128           // cols per B tile (32 KB)
#define GNT    (GSPAN / GBC) // 8 steps per strip

// ---- old fallback pipeline geometry
#define NSTRIP 2
#define SCOLS (BN / NSTRIP)
#define RPB 64
#define CT 64

typedef float4 f4;
typedef __attribute__((ext_vector_type(8))) short short8;
typedef __attribute__((ext_vector_type(4))) float f32x4;

__device__ __forceinline__ unsigned bf_rne(float f) {
  unsigned u = __float_as_uint(f);
  u += 0x7fffu + ((u >> 16) & 1u);
  return u >> 16;
}

// order-preserving float->uint map (monotone for all finite floats)
__device__ __forceinline__ unsigned fmap(float f) {
  unsigned b = __float_as_uint(f);
  return (b & 0x80000000u) ? ~b : (b | 0x80000000u);
}

// async global->LDS, 16B per lane (dest is wave-uniform base + lane*16)
__device__ __forceinline__ void gload16(const unsigned short* g,
                                        unsigned short* l) {
  __builtin_amdgcn_global_load_lds(
      (const __attribute__((address_space(1))) unsigned int*)g,
      (__attribute__((address_space(3))) unsigned int*)l, 16, 0, 0);
}

// ---------------- init: deg=1, cur=0, gmaxu=0 (re-init every call)
__global__ __launch_bounds__(256) void k_init(int* deg, int* cur,
                                              unsigned* gmaxu) {
  int i = blockIdx.x * 256 + threadIdx.x;
  if (i < BN) { deg[i] = 1; cur[i] = 0; }
  if (i < BN * 16) gmaxu[i] = 0u;    // mapped ~ -inf
}

// ---------------- x_l = x@W_l + b_l ; x_r = x@W_r + b_r  (fp32, 16 rows/block)
__global__ __launch_bounds__(256) void k_lin(const float* __restrict__ x,
    const float* __restrict__ Wl, const float* __restrict__ bl,
    const float* __restrict__ Wr, const float* __restrict__ br,
    float* __restrict__ xl, float* __restrict__ xr) {
  __shared__ __align__(16) float xst[DK][16];
  int tid = threadIdx.x;
  int r0 = blockIdx.x * 16;
  for (int i = 0; i < 2; ++i) {
    int s = tid + i * 256;
    int r = s >> 5, kq = s & 31;
    f4 v = *(const f4*)&x[(size_t)(r0 + r) * DK + kq * 4];
    xst[kq*4+0][r] = v.x; xst[kq*4+1][r] = v.y;
    xst[kq*4+2][r] = v.z; xst[kq*4+3][r] = v.w;
  }
  __syncthreads();
  float al[16], ar[16];
  #pragma unroll
  for (int r = 0; r < 16; ++r) { al[r] = 0.f; ar[r] = 0.f; }
  for (int k = 0; k < DK; ++k) {
    float wl = Wl[k * HC + tid];
    float wr = Wr[k * HC + tid];
    float xv[16];
    *(f4*)&xv[0]  = *(const f4*)&xst[k][0];
    *(f4*)&xv[4]  = *(const f4*)&xst[k][4];
    *(f4*)&xv[8]  = *(const f4*)&xst[k][8];
    *(f4*)&xv[12] = *(const f4*)&xst[k][12];
    #pragma unroll
    for (int r = 0; r < 16; ++r) { al[r] += xv[r] * wl; ar[r] += xv[r] * wr; }
  }
  float bbl = bl[tid], bbr = br[tid];
  #pragma unroll
  for (int r = 0; r < 16; ++r) {
    xl[(size_t)(r0 + r) * HC + tid] = al[r] + bbl;
    xr[(size_t)(r0 + r) * HC + tid] = ar[r] + bbr;
  }
}

// ---------------- x (fp32) -> x_bf (bf16, RNE)
__global__ __launch_bounds__(256) void k_cvt(const float* __restrict__ x,
                                             unsigned short* __restrict__ xbf) {
  size_t base = (size_t)(blockIdx.x * 256 + threadIdx.x) * 8;
  f4 a = *(const f4*)&x[base];
  f4 b = *(const f4*)&x[base + 4];
  uint4 o;
  o.x = bf_rne(a.x) | (bf_rne(a.y) << 16);
  o.y = bf_rne(a.z) | (bf_rne(a.w) << 16);
  o.z = bf_rne(b.x) | (bf_rne(b.y) << 16);
  o.w = bf_rne(b.z) | (bf_rne(b.w) << 16);
  *(uint4*)&xbf[base] = o;
}

// ---------------- streamed MFMA scorer: round-10 schedule + per-ks fragment
// reads (rounds 16/17: FETCH 174->26 MB, WRITE 327->148 MB, dur 197->183.5).
// ROUND-18 CHANGE (MODE 1 only): the fully-unrolled 8-step body (forced by
// the static-index rule for hm[t]) instantiated 8 copies of staging/LDS
// addressing -> residual ~148 MB scratch. Hit masks now go to LDS
// (hmL[GNT][512], 16 KB, declared inside the MODE-1 branch; LDS 98->114.5 KB
// keeps 1 block/CU) and MODE 1 becomes the SAME runtime-loop shape as MODE 0.
// Each thread writes/reads only its own hmL slot -> no extra sync needed.
// MODE 0 byte-identical to the measured-183.5 form. Candidate set unchanged
// (same compares, same per-thread flush order; k_rank order-independent).
// Per block: 128-row panel vs 1024-col strip, 8 steps of 128 cols, 8 waves
// (2x4 of 64x32 tiles). B tiles double-buffered with global_load_lds issued
// before compute, one __syncthreads per step. Per ks-slice: read afq[4] +
// bfq[2] from LDS, issue 8 MFMAs (ks-ascending chain per acc cell).
// acc[m][n][r]: row = q0+64wm+16m+4th+r, col = c0+128t+32wn+16n+tq.
template <int MODE>
__global__ __launch_bounds__(512, 1) void k_gemm_t(
    const unsigned short* __restrict__ xbf, unsigned* __restrict__ gmaxu,
    const unsigned* __restrict__ tau_u, int* __restrict__ cnt,
    int* __restrict__ cand) {
  __shared__ __align__(16) unsigned short As[128 * DK];
  __shared__ __align__(16) unsigned short Bs0[128 * DK];
  __shared__ __align__(16) unsigned short Bs1[128 * DK];
  __shared__ float red[4][128];
  int tid = threadIdx.x;
  int q0 = blockIdx.y * 128;
  int c0 = blockIdx.x * GSPAN;
  int lane = tid & 63;
  int wid = tid >> 6;
  int wm = wid & 1, wn = wid >> 1;
  int tq = lane & 15, th = lane >> 4;

  // t-invariant staging geometry: slot = tid + i*512 -> (row, 16B chunk)
  // source chunk pre-swizzled so linear LDS dest == XOR-swizzled layout
  int soff[4];       // element offset within a 128-row tile
  #pragma unroll
  for (int i = 0; i < 4; ++i) {
    int slot = tid + i * 512;
    int row = slot >> 4, c8 = slot & 15;
    soff[i] = row * DK + ((c8 ^ (row & 7)) * 8);
  }
  // prologue: stage A panel + B tile 0
  #pragma unroll
  for (int i = 0; i < 4; ++i)
    gload16(&xbf[(size_t)q0 * DK + soff[i]], &As[(tid + i * 512) * 8]);
  #pragma unroll
  for (int i = 0; i < 4; ++i)
    gload16(&xbf[(size_t)c0 * DK + soff[i]], &Bs0[(tid + i * 512) * 8]);
  __syncthreads();   // drains vmcnt -> A and B0 resident

  float gmx[4][4];   // MODE 0: lane-local running max
  float tauf[4][4];  // MODE 1: float-domain threshold
  if constexpr (MODE == 0) {
    #pragma unroll
    for (int m = 0; m < 4; ++m)
      #pragma unroll
      for (int r = 0; r < 4; ++r) gmx[m][r] = -3.0e38f;
  } else {
    #pragma unroll
    for (int m = 0; m < 4; ++m)
      #pragma unroll
      for (int r = 0; r < 4; ++r) {
        unsigned tu = tau_u[q0 + 64*wm + 16*m + 4*th + r];
        tauf[m][r] = __uint_as_float(
            (tu >= 0x80000000u) ? (tu ^ 0x80000000u) : ~tu);
      }
  }

  if constexpr (MODE == 0) {
    // ---- runtime loop (round-17 measured form, byte-identical)
    unsigned short* Bc = Bs0;
    unsigned short* Bn = Bs1;
    for (int t = 0; t < GNT; ++t) {
      if (t + 1 < GNT) {
        size_t gb = (size_t)(c0 + (t + 1) * GBC) * DK;
        #pragma unroll
        for (int i = 0; i < 4; ++i)
          gload16(&xbf[gb + soff[i]], &Bn[(tid + i * 512) * 8]);
      }
      f32x4 acc[4][2];
      #pragma unroll
      for (int m = 0; m < 4; ++m)
        #pragma unroll
        for (int n = 0; n < 2; ++n) {
          acc[m][n][0] = 0.f; acc[m][n][1] = 0.f;
          acc[m][n][2] = 0.f; acc[m][n][3] = 0.f;
        }
      #pragma unroll
      for (int ks = 0; ks < 4; ++ks) {
        short8 afq[4];
        #pragma unroll
        for (int m = 0; m < 4; ++m) {
          int ra = 64 * wm + 16 * m + tq;
          afq[m] = *(const short8*)&As[ra * DK +
                       (((ks*4+th) ^ (ra & 7)) * 8)];
        }
        short8 bfq[2];
        #pragma unroll
        for (int n = 0; n < 2; ++n) {
          int rb = 32 * wn + 16 * n + tq;
          bfq[n] = *(const short8*)&Bc[rb * DK +
                       (((ks*4+th) ^ (rb & 7)) * 8)];
        }
        #pragma unroll
        for (int m = 0; m < 4; ++m)
          #pragma unroll
          for (int n = 0; n < 2; ++n)
            acc[m][n] = __builtin_amdgcn_mfma_f32_16x16x32_bf16(
                afq[m], bfq[n], acc[m][n], 0, 0, 0);
      }
      #pragma unroll
      for (int m = 0; m < 4; ++m)
        #pragma unroll
        for (int r = 0; r < 4; ++r)
          gmx[m][r] = fmaxf(gmx[m][r], fmaxf(acc[m][0][r], acc[m][1][r]));
      __syncthreads();
      unsigned short* tb = Bc; Bc = Bn; Bn = tb;
    }
    // reduce over tq lanes, then across wn waves via LDS; plain store
    #pragma unroll
    for (int m = 0; m < 4; ++m)
      #pragma unroll
      for (int r = 0; r < 4; ++r) {
        float v = gmx[m][r];
        #pragma unroll
        for (int w = 1; w < 16; w <<= 1) v = fmaxf(v, __shfl_xor(v, w, 64));
        if (tq == 0) red[wn][64*wm + 16*m + 4*th + r] = v;
      }
    __syncthreads();
    if (tid < 128) {
      float v = fmaxf(fmaxf(red[0][tid], red[1][tid]),
                      fmaxf(red[2][tid], red[3][tid]));
      gmaxu[(q0 + tid) * 16 + blockIdx.x] = fmap(v);
    }
  } else {
    // ---- runtime loop with hit masks in LDS (de-unrolled; each thread
    // touches only hmL[t][tid] -> thread-ordered LDS, no extra sync)
    __shared__ unsigned hmL[GNT][512];
    unsigned short* Bc = Bs0;
    unsigned short* Bn = Bs1;
    for (int t = 0; t < GNT; ++t) {
      if (t + 1 < GNT) {
        size_t gb = (size_t)(c0 + (t + 1) * GBC) * DK;
        #pragma unroll
        for (int i = 0; i < 4; ++i)
          gload16(&xbf[gb + soff[i]], &Bn[(tid + i * 512) * 8]);
      }
      f32x4 acc[4][2];
      #pragma unroll
      for (int m = 0; m < 4; ++m)
        #pragma unroll
        for (int n = 0; n < 2; ++n) {
          acc[m][n][0] = 0.f; acc[m][n][1] = 0.f;
          acc[m][n][2] = 0.f; acc[m][n][3] = 0.f;
        }
      #pragma unroll
      for (int ks = 0; ks < 4; ++ks) {
        short8 afq[4];
        #pragma unroll
        for (int m = 0; m < 4; ++m) {
          int ra = 64 * wm + 16 * m + tq;
          afq[m] = *(const short8*)&As[ra * DK +
                       (((ks*4+th) ^ (ra & 7)) * 8)];
        }
        short8 bfq[2];
        #pragma unroll
        for (int n = 0; n < 2; ++n) {
          int rb = 32 * wn + 16 * n + tq;
          bfq[n] = *(const short8*)&Bc[rb * DK +
                       (((ks*4+th) ^ (rb & 7)) * 8)];
        }
        #pragma unroll
        for (int m = 0; m < 4; ++m)
          #pragma unroll
          for (int n = 0; n < 2; ++n)
            acc[m][n] = __builtin_amdgcn_mfma_f32_16x16x32_bf16(
                afq[m], bfq[n], acc[m][n], 0, 0, 0);
      }
      unsigned mm = 0;
      #pragma unroll
      for (int m = 0; m < 4; ++m)
        #pragma unroll
        for (int r = 0; r < 4; ++r)
          #pragma unroll
          for (int n = 0; n < 2; ++n)
            mm |= (acc[m][n][r] >= tauf[m][r])
                      ? (1u << ((m << 3) | (r << 1) | n)) : 0u;
      hmL[t][tid] = mm;
      __syncthreads();
      unsigned short* tb = Bc; Bc = Bn; Bn = tb;
    }
    // deferred candidate flush: atomics OUTSIDE the pipelined loop.
    // Same set as inline (same compares), order changes only.
    for (int t = 0; t < GNT; ++t) {
      unsigned mm = hmL[t][tid];
      while (mm) {
        int b = __ffs(mm) - 1;
        mm &= mm - 1;
        int m = b >> 3, r = (b >> 1) & 3, n = b & 1;
        int row = q0 + 64*wm + 16*m + 4*th + r;
        int col = c0 + t * GBC + 32*wn + 16*n + tq;
        int slot = atomicAdd(&cnt[row], 1);
        if (slot < CAP) cand[(size_t)row * CAP + slot] = col;
      }
    }
  }
}

// ---------------- tau = min of 16 group maxes (<= true 16th value, provably);
// also zero candidate counters
__global__ __launch_bounds__(256) void k_tau(const unsigned* __restrict__ gmaxu,
    unsigned* __restrict__ tau_u, int* __restrict__ cnt) {
  int row = blockIdx.x * 256 + threadIdx.x;
  unsigned t = 0xFFFFFFFFu;
  #pragma unroll
  for (int g = 0; g < 16; ++g) t = min(t, gmaxu[row * 16 + g]);
  tau_u[row] = t;
  cnt[row] = 0;
}

// ---------------- TWO-PHASE exact rescore (used when workspace allows the
// +32 MB score buffer). Splits score (needs pre[8]/fmaf chains) from rank
// (needs sv/cc/rk arrays) so NEITHER kernel carries the union register set.
// Round-14 measured: both below the 195-us top-5 cutoff; total 668 us.
// PHASE A: one block per row, 512 threads, one candidate per thread.
// Dot = sequential fmaf chain (round-3-proven exact match vs the reference;
// summation order MUST NOT change). (512,4) caps VGPR at 128 (under cliff).
__global__ __launch_bounds__(512, 4) void k_score(const float* __restrict__ x,
    const int* __restrict__ cand, const int* __restrict__ cnt,
    float* __restrict__ svbuf) {
  __shared__ __align__(16) float arow[DK];
  int row = blockIdx.x;
  int i = threadIdx.x;
  int n = cnt[row];
  if (i < 32)
    *(f4*)&arow[i * 4] = *(const f4*)&x[(size_t)row * DK + i * 4];
  __syncthreads();
  if (n > CAP || i >= n) return;     // overflow rows: k_exact_of
  const f4* as = (const f4*)arow;
  int col = cand[(size_t)row * CAP + i];
  const f4* b4 = (const f4*)&x[(size_t)col * DK];
  f4 pre[8];
  #pragma unroll
  for (int q = 0; q < 8; ++q) pre[q] = b4[q * 4];     // one load per 64B line
  float t = 0.f;
  #pragma unroll
  for (int k = 0; k < 32; ++k) {
    f4 a = as[k];
    f4 b = ((k & 3) == 0) ? pre[k >> 2] : b4[k];      // static select (unroll)
    t = fmaf(a.x, b.x, t); t = fmaf(a.y, b.y, t);
    t = fmaf(a.z, b.z, t); t = fmaf(a.w, b.w, t);
  }
  svbuf[(size_t)row * CAP + i] = t;
}

// PHASE B: one wave per row; coalesced score/col loads; chunked broadcast
// rank with the SAME sentinels and (value desc, col asc) comparison as the
// proven combined kernel -> bitwise-identical idx. ~24-reg arrays + temps,
// under the 128 cliff, no spills.
__global__ __launch_bounds__(256) void k_rank(const float* __restrict__ svbuf,
    const int* __restrict__ cand, const int* __restrict__ cnt,
    int* __restrict__ idx) {
  int lane = threadIdx.x & 63, wid = threadIdx.x >> 6;
  int row = blockIdx.x * 4 + wid;
  int n = cnt[row];
  if (n > CAP) return;               // k_exact_of covers this row
  int NCH = (n + 63) >> 6;
  float sv[8]; int cc[8]; int rk[8];
  #pragma unroll
  for (int p = 0; p < 8; ++p) {
    sv[p] = -3.0e38f; cc[p] = 0x7fffffff; rk[p] = 0;
  }
  #pragma unroll
  for (int p = 0; p < 8; ++p) {
    if (p < NCH) {
      int i = p * 64 + lane;
      if (i < n) {
        sv[p] = svbuf[(size_t)row * CAP + i];
        cc[p] = cand[(size_t)row * CAP + i];
      }
    }
  }
  #pragma unroll
  for (int q = 0; q < 8; ++q) {
    if (q < NCH) {
      for (int l = 0; l < 64; ++l) {
        float vj = __shfl(sv[q], l, 64);
        int   cj = __shfl(cc[q], l, 64);
        #pragma unroll
        for (int p = 0; p < 8; ++p)
          rk[p] += (vj > sv[p] || (vj == sv[p] && cj < cc[p])) ? 1 : 0;
      }
    }
  }
  #pragma unroll
  for (int p = 0; p < 8; ++p) {
    int i = p * 64 + lane;
    if (p < NCH && i < n && rk[p] < TK) idx[(size_t)row * TK + rk[p]] = cc[p];
  }
}

// ---------------- exact fp32-chain rescore of candidates -> top-16 (TIER-2:
// used when workspace lacks the score buffer; round-13 measured 228 us).
__global__ __launch_bounds__(256, 4) void k_exact(const float* __restrict__ x,
    const int* __restrict__ cand, const int* __restrict__ cnt,
    int* __restrict__ idx) {
  __shared__ __align__(16) float arow[4][DK];
  int lane = threadIdx.x & 63, wid = threadIdx.x >> 6;
  int row = blockIdx.x * 4 + wid;
  int n = cnt[row];
  // stage this wave's query row into LDS (all later reads are broadcasts)
  if (lane < 32)
    *(f4*)&arow[wid][lane * 4] = *(const f4*)&x[(size_t)row * DK + lane * 4];
  __syncthreads();
  if (n > CAP) return;               // k_exact_of covers this row
  const f4* as = (const f4*)&arow[wid][0];

  if (n <= 64) {
    // ---- fast path: one candidate per lane
    bool ok = lane < n;
    int col = ok ? cand[(size_t)row * CAP + lane] : row;
    const f4* b4 = (const f4*)&x[(size_t)col * DK];
    f4 pre[8];
    #pragma unroll
    for (int q = 0; q < 8; ++q) pre[q] = b4[q * 4];   // one load per 64B line
    float t = 0.f;
    #pragma unroll
    for (int k = 0; k < 32; ++k) {
      f4 a = as[k];
      f4 b = ((k & 3) == 0) ? pre[k >> 2] : b4[k];    // static select (unroll)
      t = fmaf(a.x, b.x, t); t = fmaf(a.y, b.y, t);
      t = fmaf(a.z, b.z, t); t = fmaf(a.w, b.w, t);
    }
    float sv = ok ? t : -3.0e38f;
    int cc = ok ? col : 0x7fffffff;
    int rk = 0;
    for (int l = 0; l < 64; ++l) {
      float vj = __shfl(sv, l, 64);
      int   cj = __shfl(cc, l, 64);
      rk += (vj > sv || (vj == sv && cj < cc)) ? 1 : 0;
    }
    if (ok && rk < TK) idx[(size_t)row * TK + rk] = cc;
  } else {
    // ---- general path (64 < n <= CAP): chunked, same structure
    int NCH = (n + 63) >> 6;
    float sv[8]; int cc[8]; int rk[8];
    #pragma unroll
    for (int p = 0; p < 8; ++p) {
      sv[p] = -3.0e38f; cc[p] = 0x7fffffff; rk[p] = 0;
    }
    #pragma unroll
    for (int p = 0; p < 8; ++p) {
      if (p < NCH) {
        int i = p * 64 + lane;
        bool ok = i < n;
        int col = ok ? cand[(size_t)row * CAP + i] : row;
        const f4* b4 = (const f4*)&x[(size_t)col * DK];
        f4 pre[8];
        #pragma unroll
        for (int q = 0; q < 8; ++q) pre[q] = b4[q * 4];
        float t = 0.f;
        #pragma unroll
        for (int k = 0; k < 32; ++k) {
          f4 a = as[k];
          f4 b = ((k & 3) == 0) ? pre[k >> 2] : b4[k];
          t = fmaf(a.x, b.x, t); t = fmaf(a.y, b.y, t);
          t = fmaf(a.z, b.z, t); t = fmaf(a.w, b.w, t);
        }
        if (ok) { sv[p] = t; cc[p] = col; }
      }
    }
    #pragma unroll
    for (int q = 0; q < 8; ++q) {
      if (q < NCH) {
        for (int l = 0; l < 64; ++l) {
          float vj = __shfl(sv[q], l, 64);
          int   cj = __shfl(cc[q], l, 64);
          #pragma unroll
          for (int p = 0; p < 8; ++p)
            rk[p] += (vj > sv[p] || (vj == sv[p] && cj < cc[p])) ? 1 : 0;
        }
      }
    }
    #pragma unroll
    for (int p = 0; p < 8; ++p) {
      int i = p * 64 + lane;
      if (p < NCH && i < n && rk[p] < TK) idx[(size_t)row * TK + rk[p]] = cc[p];
    }
  }
}

// ---------------- overflow insurance: exact full-row scan for rows with
// cnt > CAP (statistically never taken; all blocks early-exit otherwise)
__global__ __launch_bounds__(256) void k_exact_of(const float* __restrict__ x,
    const int* __restrict__ cnt, int* __restrict__ idx) {
  int lane = threadIdx.x & 63, wid = threadIdx.x >> 6;
  int row = blockIdx.x * 4 + wid;
  if (cnt[row] <= CAP) return;
  const f4* a4 = (const f4*)&x[(size_t)row * DK];
  float bv[16]; int bc[16];
  #pragma unroll
  for (int i = 0; i < 16; ++i) { bv[i] = -3.0e38f; bc[i] = 0x7fffffff; }
  for (int c = lane; c < BN; c += 64) {
    const f4* b4 = (const f4*)&x[(size_t)c * DK];
    float s = 0.f;
    #pragma unroll
    for (int k = 0; k < 32; ++k) {
      f4 a = a4[k], b = b4[k];
      s = fmaf(a.x, b.x, s); s = fmaf(a.y, b.y, s);
      s = fmaf(a.z, b.z, s); s = fmaf(a.w, b.w, s);
    }
    if (s > bv[15] || (s == bv[15] && c < bc[15])) {
      bv[15] = s; bc[15] = c;
      #pragma unroll
      for (int i = 15; i > 0; --i) {
        bool sw = bv[i] > bv[i-1] || (bv[i] == bv[i-1] && bc[i] < bc[i-1]);
        if (sw) {
          float tv = bv[i]; bv[i] = bv[i-1]; bv[i-1] = tv;
          int tc = bc[i]; bc[i] = bc[i-1]; bc[i-1] = tc;
        }
      }
    }
  }
  for (int t = 0; t < TK; ++t) {
    float mv = bv[0]; int mc = bc[0];
    #pragma unroll
    for (int w = 1; w < 64; w <<= 1) {
      float ov = __shfl_xor(mv, w, 64);
      int   oc = __shfl_xor(mc, w, 64);
      if (ov > mv || (ov == mv && oc < mc)) { mv = ov; mc = oc; }
    }
    if (bv[0] == mv && bc[0] == mc) {
      idx[(size_t)row * TK + t] = mc;
      #pragma unroll
      for (int i = 0; i < 15; ++i) { bv[i] = bv[i+1]; bc[i] = bc[i+1]; }
      bv[15] = -3.0e38f; bc[15] = 0x7fffffff;
    }
  }
}

// ================= OLD fallback pipeline (round-3, passing) =================
__global__ __launch_bounds__(256) void k_sim(const float* __restrict__ x,
    int* __restrict__ candC) {
  __shared__ __align__(16) float At[DK][RPB];
  __shared__ __align__(16) float Bt[CT][DK];
  int tid = threadIdx.x;
  int rowblk = blockIdx.x & 255;
  int strip  = blockIdx.x >> 8;
  int r0 = rowblk * RPB;
  int tx = tid & 15, ty = tid >> 4;
  int lane = tid & 63;
  int gbase = lane & 48;
  for (int i = 0; i < 8; ++i) {
    int s = tid + i * 256;
    int r = s >> 5, kq = s & 31;
    f4 v = *(const f4*)&x[(size_t)(r0 + r) * DK + kq * 4];
    At[kq*4+0][r] = v.x; At[kq*4+1][r] = v.y;
    At[kq*4+2][r] = v.z; At[kq*4+3][r] = v.w;
  }
  float listV[4]; int listC[4];
  #pragma unroll
  for (int rr = 0; rr < 4; ++rr) { listV[rr] = -3.0e38f; listC[rr] = 0; }
  __syncthreads();
  for (int ct = 0; ct < SCOLS / CT; ++ct) {
    int c0 = strip * SCOLS + ct * CT;
    for (int i = 0; i < 8; ++i) {
      int s = tid + i * 256;
      int c = s >> 5, kq = s & 31;
      f4 v = *(const f4*)&x[(size_t)(c0 + c) * DK + kq * 4];
      ((f4*)&Bt[c][0])[kq ^ (c & 7)] = v;
    }
    __syncthreads();
    float acc[4][4];
    #pragma unroll
    for (int a = 0; a < 4; ++a)
      #pragma unroll
      for (int b = 0; b < 4; ++b) acc[a][b] = 0.f;
    #pragma unroll 2
    for (int k4 = 0; k4 < 32; ++k4) {
      float ta[4][4], tb[4][4];
      #pragma unroll
      for (int j = 0; j < 4; ++j)
        *(f4*)&ta[j][0] = *(const f4*)&At[k4*4 + j][ty*4];
      #pragma unroll
      for (int jj = 0; jj < 4; ++jj) {
        int c = tx + 16*jj;
        *(f4*)&tb[jj][0] = ((const f4*)&Bt[c][0])[k4 ^ (c & 7)];
      }
      #pragma unroll
      for (int rr = 0; rr < 4; ++rr)
        #pragma unroll
        for (int jj = 0; jj < 4; ++jj)
          acc[rr][jj] += ta[0][rr]*tb[jj][0] + ta[1][rr]*tb[jj][1]
                       + ta[2][rr]*tb[jj][2] + ta[3][rr]*tb[jj][3];
    }
    float tau[4];
    #pragma unroll
    for (int rr = 0; rr < 4; ++rr) tau[rr] = __shfl(listV[rr], 15, 16);
    #pragma unroll
    for (int rr = 0; rr < 4; ++rr) {
      #pragma unroll
      for (int jj = 0; jj < 4; ++jj) {
        float v = acc[rr][jj];
        unsigned long long bal = __ballot(v > tau[rr]);
        unsigned bits = (unsigned)((bal >> gbase) & 0xffffULL);
        while (bits) {
          int l = __ffs(bits) - 1;
          float vb = __shfl(v, l, 16);
          int colb = c0 + l + 16*jj;
          unsigned long long g2 = __ballot(listV[rr] > vb);
          int cnt2 = __popc((unsigned)((g2 >> gbase) & 0xffffULL));
          float sV = __shfl_up(listV[rr], 1, 16);
          int   sC = __shfl_up(listC[rr], 1, 16);
          if (tx == cnt2)      { listV[rr] = vb; listC[rr] = colb; }
          else if (tx > cnt2)  { listV[rr] = sV; listC[rr] = sC; }
          bits &= bits - 1;
        }
      }
    }
    __syncthreads();
  }
  #pragma unroll
  for (int rr = 0; rr < 4; ++rr) {
    int row = r0 + ty * 4 + rr;
    candC[row * (NSTRIP * TK) + strip * TK + tx] = listC[rr];
  }
}

__global__ __launch_bounds__(256) void k_rescore(const float* __restrict__ x,
    const int* __restrict__ candC, int* __restrict__ idx) {
  int lane = threadIdx.x & 63;
  int wid  = threadIdx.x >> 6;
  int half = lane >> 5;
  int ci   = lane & 31;
  int row  = (blockIdx.x * 4 + wid) * 2 + half;
  int col  = candC[row * (NSTRIP * TK) + ci];
  const f4* a4 = (const f4*)&x[(size_t)row * DK];
  const f4* b4 = (const f4*)&x[(size_t)col * DK];
  float s = 0.f;
  #pragma unroll
  for (int k = 0; k < 32; ++k) {
    f4 a = a4[k], b = b4[k];
    s = fmaf(a.x, b.x, s);
    s = fmaf(a.y, b.y, s);
    s = fmaf(a.z, b.z, s);
    s = fmaf(a.w, b.w, s);
  }
  int rank = 0;
  #pragma unroll
  for (int j = 0; j < 32; ++j) {
    float vj = __shfl(s, j, 32);
    int   cj = __shfl(col, j, 32);
    if (vj > s || (vj == s && cj < col)) rank++;
  }
  if (rank < TK) idx[row * TK + rank] = col;
}
// ================= end old fallback =================

// ---------------- CSR by dst: count, scan, fill
__global__ __launch_bounds__(256) void k_count(const int* __restrict__ idx,
                                               int* __restrict__ deg) {
  int i = blockIdx.x * 256 + threadIdx.x;
  int b = i >> 4;
  int t = idx[i];
  if (t != b) atomicAdd(&deg[t], 1);
}

__global__ __launch_bounds__(1024) void k_scan(const int* __restrict__ deg,
                                               int* __restrict__ off) {
  __shared__ int sdat[1024];
  int tid = threadIdx.x;
  int carry = 0;
  for (int ch = 0; ch < BN / 1024; ++ch) {
    int i = ch * 1024 + tid;
    int v = deg[i];
    sdat[tid] = v;
    __syncthreads();
    for (int o = 1; o < 1024; o <<= 1) {
      int t = (tid >= o) ? sdat[tid - o] : 0;
      __syncthreads();
      sdat[tid] += t;
      __syncthreads();
    }
    off[i] = sdat[tid] - v + carry;
    int tot = sdat[1023];
    __syncthreads();
    carry += tot;
  }
  if (tid == 0) off[BN] = carry;
}

__global__ __launch_bounds__(256) void k_fill(const int* __restrict__ idx,
    const int* __restrict__ off, int* __restrict__ cur, int* __restrict__ csr) {
  int i = blockIdx.x * 256 + threadIdx.x;
  if (i >= BN * (TK + 1)) return;
  int b = i / (TK + 1);
  int j = i - b * (TK + 1);
  int t;
  if (j < TK) { t = idx[b * TK + j]; if (t == b) return; }
  else t = b;
  int p = atomicAdd(&cur[t], 1);
  csr[off[t] + p] = b;
}

// ---------------- per-dst online segment softmax + aggregation
__global__ __launch_bounds__(256) void k_aggr(const float* __restrict__ xl,
    const float* __restrict__ xr, const float* __restrict__ att,
    const float* __restrict__ bias, const int* __restrict__ off,
    const int* __restrict__ csr, float* __restrict__ out) {
  int t = blockIdx.x;
  int tid = threadIdx.x;
  int o0 = off[t], o1 = off[t + 1];
  float xrv = xr[(size_t)t * HC + tid];
  float av = att[tid];
  float m = -3.0e38f, den = 0.f, acc = 0.f;
  for (int e = o0; e < o1; ++e) {
    int s = csr[e];
    float xlv = xl[(size_t)s * HC + tid];
    float z = xlv + xrv;
    z = (z > 0.f) ? z : 0.2f * z;
    float sc = z * av;
    #pragma unroll
    for (int w = 1; w < 64; w <<= 1) sc += __shfl_xor(sc, w, 64);
    if (sc > m) {
      float r = __expf(m - sc);
      den *= r; acc *= r; m = sc;
    }
    float p = __expf(sc - m);
    den += p;
    acc += p * xlv;
  }
  out[(size_t)t * HC + tid] = acc / den + bias[tid];
}

extern "C" void kernel_launch(void* const* d_in, const int* in_sizes, int n_in,
                              void* d_out, int out_size, void* d_ws, size_t ws_size,
                              hipStream_t stream) {
  const float* x   = (const float*)d_in[0];
  const float* Wl  = (const float*)d_in[1];
  const float* bl  = (const float*)d_in[2];
  const float* Wr  = (const float*)d_in[3];
  const float* br  = (const float*)d_in[4];
  const float* att = (const float*)d_in[5];
  const float* bias= (const float*)d_in[6];
  float* out = (float*)d_out;

  // ---- new-path workspace layout (~75 MB) + optional score buffer (32 MB)
  const size_t need =
      (size_t)BN*HC*4*2          // xl, xr
    + (size_t)BN*DK*2            // xbf
    + (size_t)BN*16*4            // gmaxu
    + (size_t)BN*4               // tau_u
    + (size_t)BN*4               // cnt
    + (size_t)BN*CAP*4           // cand
    + (size_t)BN*TK*4            // idx
    + (size_t)BN*4*3 + 64        // deg, cur, off(+1)
    + (size_t)BN*(TK+1)*4;       // csr
  const size_t need2 = need + (size_t)BN*CAP*4;   // + svbuf (two-phase exact)

  if (ws_size >= need) {
    char* p = (char*)d_ws;
    float* xl = (float*)p;                    p += (size_t)BN*HC*4;
    float* xr = (float*)p;                    p += (size_t)BN*HC*4;
    unsigned short* xbf = (unsigned short*)p; p += (size_t)BN*DK*2;
    unsigned* gmaxu = (unsigned*)p;           p += (size_t)BN*16*4;
    unsigned* tau_u = (unsigned*)p;           p += (size_t)BN*4;
    int* cnt = (int*)p;                       p += (size_t)BN*4;
    int* cand = (int*)p;                      p += (size_t)BN*CAP*4;
    int* idx = (int*)p;                       p += (size_t)BN*TK*4;
    int* deg = (int*)p;                       p += (size_t)BN*4;
    int* off = (int*)p;                       p += (size_t)(BN+1)*4 + 60;
    int* cur = (int*)p;                       p += (size_t)BN*4;
    int* csr = (int*)p;                       p += (size_t)BN*(TK+1)*4;
    float* svbuf = (float*)p;                 // valid only if ws_size >= need2

    hipLaunchKernelGGL(k_init, dim3(BN*16/256), dim3(256), 0, stream,
                       deg, cur, gmaxu);
    hipLaunchKernelGGL(k_lin,  dim3(BN/16),  dim3(256), 0, stream,
                       x, Wl, bl, Wr, br, xl, xr);
    hipLaunchKernelGGL(k_cvt,  dim3(BN*DK/(256*8)), dim3(256), 0, stream, x, xbf);
    hipLaunchKernelGGL((k_gemm_t<0>), dim3(GSPLIT, BN/128), dim3(512), 0, stream,
                       xbf, gmaxu, (const unsigned*)nullptr,
                       (int*)nullptr, (int*)nullptr);
    hipLaunchKernelGGL(k_tau,  dim3(BN/256), dim3(256), 0, stream,
                       gmaxu, tau_u, cnt);
    hipLaunchKernelGGL((k_gemm_t<1>), dim3(GSPLIT, BN/128), dim3(512), 0, stream,
                       xbf, (unsigned*)nullptr, tau_u, cnt, cand);
    if (ws_size >= need2) {
      // two-phase exact rescore (high-TLP score pass + light rank pass)
      hipLaunchKernelGGL(k_score, dim3(BN), dim3(512), 0, stream,
                         x, cand, cnt, svbuf);
      hipLaunchKernelGGL(k_rank,  dim3(BN/4), dim3(256), 0, stream,
                         svbuf, cand, cnt, idx);
    } else {
      // tier-2: round-13 measured combined kernel (228 us)
      hipLaunchKernelGGL(k_exact, dim3(BN/4), dim3(256), 0, stream,
                         x, cand, cnt, idx);
    }
    hipLaunchKernelGGL(k_exact_of, dim3(BN/4), dim3(256), 0, stream,
                       x, cnt, idx);
    hipLaunchKernelGGL(k_count, dim3(BN*TK/256), dim3(256), 0, stream, idx, deg);
    hipLaunchKernelGGL(k_scan,  dim3(1), dim3(1024), 0, stream, deg, off);
    hipLaunchKernelGGL(k_fill,  dim3((BN*(TK+1))/256), dim3(256), 0, stream,
                       idx, off, cur, csr);
    hipLaunchKernelGGL(k_aggr,  dim3(BN), dim3(256), 0, stream,
                       xl, xr, att, bias, off, csr, out);
  } else {
    // ---- fallback: round-3 passing pipeline (~40 MB)
    float* xl    = (float*)d_ws;
    float* xr    = xl + (size_t)BN * HC;
    int* candC   = (int*)(xr + (size_t)BN * HC);
    int* idx     = candC + (size_t)BN * NSTRIP * TK;
    int* deg     = idx + (size_t)BN * TK;
    int* off     = deg + BN;
    int* cur     = off + (BN + 1);
    int* csr     = cur + BN;
    unsigned* gmaxu_dummy = (unsigned*)(csr + (size_t)BN * (TK + 1));

    hipLaunchKernelGGL(k_init,  dim3(BN/256), dim3(256), 0, stream,
                       deg, cur, gmaxu_dummy);
    hipLaunchKernelGGL(k_lin,   dim3(BN/16),  dim3(256), 0, stream,
                       x, Wl, bl, Wr, br, xl, xr);
    hipLaunchKernelGGL(k_sim,   dim3(NSTRIP*(BN/RPB)), dim3(256), 0, stream,
                       x, candC);
    hipLaunchKernelGGL(k_rescore, dim3(BN/8), dim3(256), 0, stream,
                       x, candC, idx);
    hipLaunchKernelGGL(k_count, dim3(BN*TK/256), dim3(256), 0, stream, idx, deg);
    hipLaunchKernelGGL(k_scan,  dim3(1), dim3(1024), 0, stream, deg, off);
    hipLaunchKernelGGL(k_fill,  dim3((BN*(TK+1))/256), dim3(256), 0, stream,
                       idx, off, cur, csr);
    hipLaunchKernelGGL(k_aggr,  dim3(BN), dim3(256), 0, stream,
                       xl, xr, att, bias, off, csr, out);
  }
}

// Round 19
// 645.083 us; speedup vs baseline: 1.0396x; 1.0280x over previous
//
#include <hip/hip_runtime.h>
#include <math.h>

// Problem constants (fixed by the reference; k input is ignored, always 16)
#define BN 16384
#define DK 128
#define HN 4
#define CN 64
#define HC 256
#define TK 16
#define CAP 512              // candidate buffer capacity per row

// ---- streamed GEMM geometry: 128-row panel x 1024-col strip per block
#define GSPLIT 16            // column strips
#define GSPAN  1024          // cols per strip (= one gmax group)
#define GBC    128           // cols per B tile (32 KB)
#define GNT    (GSPAN / GBC) // 8 steps per strip

// ---- old fallback pipeline geometry
#define NSTRIP 2
#define SCOLS (BN / NSTRIP)
#define RPB 64
#define CT 64

typedef float4 f4;
typedef __attribute__((ext_vector_type(8))) short short8;
typedef __attribute__((ext_vector_type(4))) float f32x4;

__device__ __forceinline__ unsigned bf_rne(float f) {
  unsigned u = __float_as_uint(f);
  u += 0x7fffu + ((u >> 16) & 1u);
  return u >> 16;
}

// order-preserving float->uint map (monotone for all finite floats)
__device__ __forceinline__ unsigned fmap(float f) {
  unsigned b = __float_as_uint(f);
  return (b & 0x80000000u) ? ~b : (b | 0x80000000u);
}

// async global->LDS, 16B per lane (dest is wave-uniform base + lane*16)
__device__ __forceinline__ void gload16(const unsigned short* g,
                                        unsigned short* l) {
  __builtin_amdgcn_global_load_lds(
      (const __attribute__((address_space(1))) unsigned int*)g,
      (__attribute__((address_space(3))) unsigned int*)l, 16, 0, 0);
}

// ---------------- init: deg=1, cur=0, gmaxu=0 (re-init every call)
__global__ __launch_bounds__(256) void k_init(int* deg, int* cur,
                                              unsigned* gmaxu) {
  int i = blockIdx.x * 256 + threadIdx.x;
  if (i < BN) { deg[i] = 1; cur[i] = 0; }
  if (i < BN * 16) gmaxu[i] = 0u;    // mapped ~ -inf
}

// ---------------- x_l = x@W_l + b_l ; x_r = x@W_r + b_r  (fp32, 16 rows/block)
__global__ __launch_bounds__(256) void k_lin(const float* __restrict__ x,
    const float* __restrict__ Wl, const float* __restrict__ bl,
    const float* __restrict__ Wr, const float* __restrict__ br,
    float* __restrict__ xl, float* __restrict__ xr) {
  __shared__ __align__(16) float xst[DK][16];
  int tid = threadIdx.x;
  int r0 = blockIdx.x * 16;
  for (int i = 0; i < 2; ++i) {
    int s = tid + i * 256;
    int r = s >> 5, kq = s & 31;
    f4 v = *(const f4*)&x[(size_t)(r0 + r) * DK + kq * 4];
    xst[kq*4+0][r] = v.x; xst[kq*4+1][r] = v.y;
    xst[kq*4+2][r] = v.z; xst[kq*4+3][r] = v.w;
  }
  __syncthreads();
  float al[16], ar[16];
  #pragma unroll
  for (int r = 0; r < 16; ++r) { al[r] = 0.f; ar[r] = 0.f; }
  for (int k = 0; k < DK; ++k) {
    float wl = Wl[k * HC + tid];
    float wr = Wr[k * HC + tid];
    float xv[16];
    *(f4*)&xv[0]  = *(const f4*)&xst[k][0];
    *(f4*)&xv[4]  = *(const f4*)&xst[k][4];
    *(f4*)&xv[8]  = *(const f4*)&xst[k][8];
    *(f4*)&xv[12] = *(const f4*)&xst[k][12];
    #pragma unroll
    for (int r = 0; r < 16; ++r) { al[r] += xv[r] * wl; ar[r] += xv[r] * wr; }
  }
  float bbl = bl[tid], bbr = br[tid];
  #pragma unroll
  for (int r = 0; r < 16; ++r) {
    xl[(size_t)(r0 + r) * HC + tid] = al[r] + bbl;
    xr[(size_t)(r0 + r) * HC + tid] = ar[r] + bbr;
  }
}

// ---------------- x (fp32) -> x_bf (bf16, RNE)
__global__ __launch_bounds__(256) void k_cvt(const float* __restrict__ x,
                                             unsigned short* __restrict__ xbf) {
  size_t base = (size_t)(blockIdx.x * 256 + threadIdx.x) * 8;
  f4 a = *(const f4*)&x[base];
  f4 b = *(const f4*)&x[base + 4];
  uint4 o;
  o.x = bf_rne(a.x) | (bf_rne(a.y) << 16);
  o.y = bf_rne(a.z) | (bf_rne(a.w) << 16);
  o.z = bf_rne(b.x) | (bf_rne(b.y) << 16);
  o.w = bf_rne(b.z) | (bf_rne(b.w) << 16);
  *(uint4*)&xbf[base] = o;
}

// ---------------- streamed MFMA scorer: round-18 form (measured 179.5 us,
// VGPR 88, WRITE 38.7 MB = scratch eliminated). ROUND-19 CHANGE: partial
// A-fragment re-hoist using the 40-reg headroom (88 -> cliff at 128).
// af2[2][4] (m=0,1; all ks; 32 regs) is read ONCE per tile; m=2,3 stay
// per-ks reads. Halves A-side LDS reads (128->64 per wave/tile) -> cuts the
// 12.6M bank-conflict cycles' A share. Live set ~120 <= 128 -> no scratch
// (go/no-go signal: WRITE_SIZE; if it balloons, revert). Scores bitwise
// identical: same LDS bytes, same ks-ascending MFMA chain per acc cell;
// both MODEs transformed identically.
// Per block: 128-row panel vs 1024-col strip, 8 steps of 128 cols, 8 waves
// (2x4 of 64x32 tiles). B tiles double-buffered with global_load_lds issued
// before compute, one __syncthreads per step.
// acc[m][n][r]: row = q0+64wm+16m+4th+r, col = c0+128t+32wn+16n+tq.
// MODE 0: runtime loop, lane-local running max, block-end reduce.
// MODE 1: runtime loop, hit masks in LDS (hmL[t][tid], own-slot only),
// atomicAdd+store flush AFTER the loop.
template <int MODE>
__global__ __launch_bounds__(512, 1) void k_gemm_t(
    const unsigned short* __restrict__ xbf, unsigned* __restrict__ gmaxu,
    const unsigned* __restrict__ tau_u, int* __restrict__ cnt,
    int* __restrict__ cand) {
  __shared__ __align__(16) unsigned short As[128 * DK];
  __shared__ __align__(16) unsigned short Bs0[128 * DK];
  __shared__ __align__(16) unsigned short Bs1[128 * DK];
  __shared__ float red[4][128];
  int tid = threadIdx.x;
  int q0 = blockIdx.y * 128;
  int c0 = blockIdx.x * GSPAN;
  int lane = tid & 63;
  int wid = tid >> 6;
  int wm = wid & 1, wn = wid >> 1;
  int tq = lane & 15, th = lane >> 4;

  // t-invariant staging geometry: slot = tid + i*512 -> (row, 16B chunk)
  // source chunk pre-swizzled so linear LDS dest == XOR-swizzled layout
  int soff[4];       // element offset within a 128-row tile
  #pragma unroll
  for (int i = 0; i < 4; ++i) {
    int slot = tid + i * 512;
    int row = slot >> 4, c8 = slot & 15;
    soff[i] = row * DK + ((c8 ^ (row & 7)) * 8);
  }
  // prologue: stage A panel + B tile 0
  #pragma unroll
  for (int i = 0; i < 4; ++i)
    gload16(&xbf[(size_t)q0 * DK + soff[i]], &As[(tid + i * 512) * 8]);
  #pragma unroll
  for (int i = 0; i < 4; ++i)
    gload16(&xbf[(size_t)c0 * DK + soff[i]], &Bs0[(tid + i * 512) * 8]);
  __syncthreads();   // drains vmcnt -> A and B0 resident

  // partial A-fragment hoist: m = 0,1 pinned in registers for all steps
  short8 af2[2][4];
  #pragma unroll
  for (int m = 0; m < 2; ++m) {
    int ra = 64 * wm + 16 * m + tq;
    #pragma unroll
    for (int ks = 0; ks < 4; ++ks)
      af2[m][ks] = *(const short8*)&As[ra * DK +
                       (((ks*4+th) ^ (ra & 7)) * 8)];
  }

  float gmx[4][4];   // MODE 0: lane-local running max
  float tauf[4][4];  // MODE 1: float-domain threshold
  if constexpr (MODE == 0) {
    #pragma unroll
    for (int m = 0; m < 4; ++m)
      #pragma unroll
      for (int r = 0; r < 4; ++r) gmx[m][r] = -3.0e38f;
  } else {
    #pragma unroll
    for (int m = 0; m < 4; ++m)
      #pragma unroll
      for (int r = 0; r < 4; ++r) {
        unsigned tu = tau_u[q0 + 64*wm + 16*m + 4*th + r];
        tauf[m][r] = __uint_as_float(
            (tu >= 0x80000000u) ? (tu ^ 0x80000000u) : ~tu);
      }
  }

  if constexpr (MODE == 0) {
    // ---- runtime loop (round-18 schedule; m=0,1 hoisted, m=2,3 per-ks)
    unsigned short* Bc = Bs0;
    unsigned short* Bn = Bs1;
    for (int t = 0; t < GNT; ++t) {
      if (t + 1 < GNT) {
        size_t gb = (size_t)(c0 + (t + 1) * GBC) * DK;
        #pragma unroll
        for (int i = 0; i < 4; ++i)
          gload16(&xbf[gb + soff[i]], &Bn[(tid + i * 512) * 8]);
      }
      f32x4 acc[4][2];
      #pragma unroll
      for (int m = 0; m < 4; ++m)
        #pragma unroll
        for (int n = 0; n < 2; ++n) {
          acc[m][n][0] = 0.f; acc[m][n][1] = 0.f;
          acc[m][n][2] = 0.f; acc[m][n][3] = 0.f;
        }
      #pragma unroll
      for (int ks = 0; ks < 4; ++ks) {
        short8 afq[2];
        #pragma unroll
        for (int m = 0; m < 2; ++m) {
          int ra = 64 * wm + 16 * (m + 2) + tq;
          afq[m] = *(const short8*)&As[ra * DK +
                       (((ks*4+th) ^ (ra & 7)) * 8)];
        }
        short8 bfq[2];
        #pragma unroll
        for (int n = 0; n < 2; ++n) {
          int rb = 32 * wn + 16 * n + tq;
          bfq[n] = *(const short8*)&Bc[rb * DK +
                       (((ks*4+th) ^ (rb & 7)) * 8)];
        }
        #pragma unroll
        for (int n = 0; n < 2; ++n) {
          acc[0][n] = __builtin_amdgcn_mfma_f32_16x16x32_bf16(
              af2[0][ks], bfq[n], acc[0][n], 0, 0, 0);
          acc[1][n] = __builtin_amdgcn_mfma_f32_16x16x32_bf16(
              af2[1][ks], bfq[n], acc[1][n], 0, 0, 0);
          acc[2][n] = __builtin_amdgcn_mfma_f32_16x16x32_bf16(
              afq[0], bfq[n], acc[2][n], 0, 0, 0);
          acc[3][n] = __builtin_amdgcn_mfma_f32_16x16x32_bf16(
              afq[1], bfq[n], acc[3][n], 0, 0, 0);
        }
      }
      #pragma unroll
      for (int m = 0; m < 4; ++m)
        #pragma unroll
        for (int r = 0; r < 4; ++r)
          gmx[m][r] = fmaxf(gmx[m][r], fmaxf(acc[m][0][r], acc[m][1][r]));
      __syncthreads();
      unsigned short* tb = Bc; Bc = Bn; Bn = tb;
    }
    // reduce over tq lanes, then across wn waves via LDS; plain store
    #pragma unroll
    for (int m = 0; m < 4; ++m)
      #pragma unroll
      for (int r = 0; r < 4; ++r) {
        float v = gmx[m][r];
        #pragma unroll
        for (int w = 1; w < 16; w <<= 1) v = fmaxf(v, __shfl_xor(v, w, 64));
        if (tq == 0) red[wn][64*wm + 16*m + 4*th + r] = v;
      }
    __syncthreads();
    if (tid < 128) {
      float v = fmaxf(fmaxf(red[0][tid], red[1][tid]),
                      fmaxf(red[2][tid], red[3][tid]));
      gmaxu[(q0 + tid) * 16 + blockIdx.x] = fmap(v);
    }
  } else {
    // ---- runtime loop with hit masks in LDS (own-slot only, no extra sync)
    __shared__ unsigned hmL[GNT][512];
    unsigned short* Bc = Bs0;
    unsigned short* Bn = Bs1;
    for (int t = 0; t < GNT; ++t) {
      if (t + 1 < GNT) {
        size_t gb = (size_t)(c0 + (t + 1) * GBC) * DK;
        #pragma unroll
        for (int i = 0; i < 4; ++i)
          gload16(&xbf[gb + soff[i]], &Bn[(tid + i * 512) * 8]);
      }
      f32x4 acc[4][2];
      #pragma unroll
      for (int m = 0; m < 4; ++m)
        #pragma unroll
        for (int n = 0; n < 2; ++n) {
          acc[m][n][0] = 0.f; acc[m][n][1] = 0.f;
          acc[m][n][2] = 0.f; acc[m][n][3] = 0.f;
        }
      #pragma unroll
      for (int ks = 0; ks < 4; ++ks) {
        short8 afq[2];
        #pragma unroll
        for (int m = 0; m < 2; ++m) {
          int ra = 64 * wm + 16 * (m + 2) + tq;
          afq[m] = *(const short8*)&As[ra * DK +
                       (((ks*4+th) ^ (ra & 7)) * 8)];
        }
        short8 bfq[2];
        #pragma unroll
        for (int n = 0; n < 2; ++n) {
          int rb = 32 * wn + 16 * n + tq;
          bfq[n] = *(const short8*)&Bc[rb * DK +
                       (((ks*4+th) ^ (rb & 7)) * 8)];
        }
        #pragma unroll
        for (int n = 0; n < 2; ++n) {
          acc[0][n] = __builtin_amdgcn_mfma_f32_16x16x32_bf16(
              af2[0][ks], bfq[n], acc[0][n], 0, 0, 0);
          acc[1][n] = __builtin_amdgcn_mfma_f32_16x16x32_bf16(
              af2[1][ks], bfq[n], acc[1][n], 0, 0, 0);
          acc[2][n] = __builtin_amdgcn_mfma_f32_16x16x32_bf16(
              afq[0], bfq[n], acc[2][n], 0, 0, 0);
          acc[3][n] = __builtin_amdgcn_mfma_f32_16x16x32_bf16(
              afq[1], bfq[n], acc[3][n], 0, 0, 0);
        }
      }
      unsigned mm = 0;
      #pragma unroll
      for (int m = 0; m < 4; ++m)
        #pragma unroll
        for (int r = 0; r < 4; ++r)
          #pragma unroll
          for (int n = 0; n < 2; ++n)
            mm |= (acc[m][n][r] >= tauf[m][r])
                      ? (1u << ((m << 3) | (r << 1) | n)) : 0u;
      hmL[t][tid] = mm;
      __syncthreads();
      unsigned short* tb = Bc; Bc = Bn; Bn = tb;
    }
    // deferred candidate flush: atomics OUTSIDE the pipelined loop.
    // Same set as inline (same compares), order changes only.
    for (int t = 0; t < GNT; ++t) {
      unsigned mm = hmL[t][tid];
      while (mm) {
        int b = __ffs(mm) - 1;
        mm &= mm - 1;
        int m = b >> 3, r = (b >> 1) & 3, n = b & 1;
        int row = q0 + 64*wm + 16*m + 4*th + r;
        int col = c0 + t * GBC + 32*wn + 16*n + tq;
        int slot = atomicAdd(&cnt[row], 1);
        if (slot < CAP) cand[(size_t)row * CAP + slot] = col;
      }
    }
  }
}

// ---------------- tau = min of 16 group maxes (<= true 16th value, provably);
// also zero candidate counters
__global__ __launch_bounds__(256) void k_tau(const unsigned* __restrict__ gmaxu,
    unsigned* __restrict__ tau_u, int* __restrict__ cnt) {
  int row = blockIdx.x * 256 + threadIdx.x;
  unsigned t = 0xFFFFFFFFu;
  #pragma unroll
  for (int g = 0; g < 16; ++g) t = min(t, gmaxu[row * 16 + g]);
  tau_u[row] = t;
  cnt[row] = 0;
}

// ---------------- TWO-PHASE exact rescore (used when workspace allows the
// +32 MB score buffer). Splits score (needs pre[8]/fmaf chains) from rank
// (needs sv/cc/rk arrays) so NEITHER kernel carries the union register set.
// Round-14 measured: both below the top-5 cutoff.
// PHASE A: one block per row, 512 threads, one candidate per thread.
// Dot = sequential fmaf chain (round-3-proven exact match vs the reference;
// summation order MUST NOT change). (512,4) caps VGPR at 128 (under cliff).
__global__ __launch_bounds__(512, 4) void k_score(const float* __restrict__ x,
    const int* __restrict__ cand, const int* __restrict__ cnt,
    float* __restrict__ svbuf) {
  __shared__ __align__(16) float arow[DK];
  int row = blockIdx.x;
  int i = threadIdx.x;
  int n = cnt[row];
  if (i < 32)
    *(f4*)&arow[i * 4] = *(const f4*)&x[(size_t)row * DK + i * 4];
  __syncthreads();
  if (n > CAP || i >= n) return;     // overflow rows: k_exact_of
  const f4* as = (const f4*)arow;
  int col = cand[(size_t)row * CAP + i];
  const f4* b4 = (const f4*)&x[(size_t)col * DK];
  f4 pre[8];
  #pragma unroll
  for (int q = 0; q < 8; ++q) pre[q] = b4[q * 4];     // one load per 64B line
  float t = 0.f;
  #pragma unroll
  for (int k = 0; k < 32; ++k) {
    f4 a = as[k];
    f4 b = ((k & 3) == 0) ? pre[k >> 2] : b4[k];      // static select (unroll)
    t = fmaf(a.x, b.x, t); t = fmaf(a.y, b.y, t);
    t = fmaf(a.z, b.z, t); t = fmaf(a.w, b.w, t);
  }
  svbuf[(size_t)row * CAP + i] = t;
}

// PHASE B: one wave per row; coalesced score/col loads; chunked broadcast
// rank with the SAME sentinels and (value desc, col asc) comparison as the
// proven combined kernel -> bitwise-identical idx. ~24-reg arrays + temps,
// under the 128 cliff, no spills.
__global__ __launch_bounds__(256) void k_rank(const float* __restrict__ svbuf,
    const int* __restrict__ cand, const int* __restrict__ cnt,
    int* __restrict__ idx) {
  int lane = threadIdx.x & 63, wid = threadIdx.x >> 6;
  int row = blockIdx.x * 4 + wid;
  int n = cnt[row];
  if (n > CAP) return;               // k_exact_of covers this row
  int NCH = (n + 63) >> 6;
  float sv[8]; int cc[8]; int rk[8];
  #pragma unroll
  for (int p = 0; p < 8; ++p) {
    sv[p] = -3.0e38f; cc[p] = 0x7fffffff; rk[p] = 0;
  }
  #pragma unroll
  for (int p = 0; p < 8; ++p) {
    if (p < NCH) {
      int i = p * 64 + lane;
      if (i < n) {
        sv[p] = svbuf[(size_t)row * CAP + i];
        cc[p] = cand[(size_t)row * CAP + i];
      }
    }
  }
  #pragma unroll
  for (int q = 0; q < 8; ++q) {
    if (q < NCH) {
      for (int l = 0; l < 64; ++l) {
        float vj = __shfl(sv[q], l, 64);
        int   cj = __shfl(cc[q], l, 64);
        #pragma unroll
        for (int p = 0; p < 8; ++p)
          rk[p] += (vj > sv[p] || (vj == sv[p] && cj < cc[p])) ? 1 : 0;
      }
    }
  }
  #pragma unroll
  for (int p = 0; p < 8; ++p) {
    int i = p * 64 + lane;
    if (p < NCH && i < n && rk[p] < TK) idx[(size_t)row * TK + rk[p]] = cc[p];
  }
}

// ---------------- exact fp32-chain rescore of candidates -> top-16 (TIER-2:
// used when workspace lacks the score buffer; round-13 measured 228 us).
__global__ __launch_bounds__(256, 4) void k_exact(const float* __restrict__ x,
    const int* __restrict__ cand, const int* __restrict__ cnt,
    int* __restrict__ idx) {
  __shared__ __align__(16) float arow[4][DK];
  int lane = threadIdx.x & 63, wid = threadIdx.x >> 6;
  int row = blockIdx.x * 4 + wid;
  int n = cnt[row];
  // stage this wave's query row into LDS (all later reads are broadcasts)
  if (lane < 32)
    *(f4*)&arow[wid][lane * 4] = *(const f4*)&x[(size_t)row * DK + lane * 4];
  __syncthreads();
  if (n > CAP) return;               // k_exact_of covers this row
  const f4* as = (const f4*)&arow[wid][0];

  if (n <= 64) {
    // ---- fast path: one candidate per lane
    bool ok = lane < n;
    int col = ok ? cand[(size_t)row * CAP + lane] : row;
    const f4* b4 = (const f4*)&x[(size_t)col * DK];
    f4 pre[8];
    #pragma unroll
    for (int q = 0; q < 8; ++q) pre[q] = b4[q * 4];   // one load per 64B line
    float t = 0.f;
    #pragma unroll
    for (int k = 0; k < 32; ++k) {
      f4 a = as[k];
      f4 b = ((k & 3) == 0) ? pre[k >> 2] : b4[k];    // static select (unroll)
      t = fmaf(a.x, b.x, t); t = fmaf(a.y, b.y, t);
      t = fmaf(a.z, b.z, t); t = fmaf(a.w, b.w, t);
    }
    float sv = ok ? t : -3.0e38f;
    int cc = ok ? col : 0x7fffffff;
    int rk = 0;
    for (int l = 0; l < 64; ++l) {
      float vj = __shfl(sv, l, 64);
      int   cj = __shfl(cc, l, 64);
      rk += (vj > sv || (vj == sv && cj < cc)) ? 1 : 0;
    }
    if (ok && rk < TK) idx[(size_t)row * TK + rk] = cc;
  } else {
    // ---- general path (64 < n <= CAP): chunked, same structure
    int NCH = (n + 63) >> 6;
    float sv[8]; int cc[8]; int rk[8];
    #pragma unroll
    for (int p = 0; p < 8; ++p) {
      sv[p] = -3.0e38f; cc[p] = 0x7fffffff; rk[p] = 0;
    }
    #pragma unroll
    for (int p = 0; p < 8; ++p) {
      if (p < NCH) {
        int i = p * 64 + lane;
        bool ok = i < n;
        int col = ok ? cand[(size_t)row * CAP + i] : row;
        const f4* b4 = (const f4*)&x[(size_t)col * DK];
        f4 pre[8];
        #pragma unroll
        for (int q = 0; q < 8; ++q) pre[q] = b4[q * 4];
        float t = 0.f;
        #pragma unroll
        for (int k = 0; k < 32; ++k) {
          f4 a = as[k];
          f4 b = ((k & 3) == 0) ? pre[k >> 2] : b4[k];
          t = fmaf(a.x, b.x, t); t = fmaf(a.y, b.y, t);
          t = fmaf(a.z, b.z, t); t = fmaf(a.w, b.w, t);
        }
        if (ok) { sv[p] = t; cc[p] = col; }
      }
    }
    #pragma unroll
    for (int q = 0; q < 8; ++q) {
      if (q < NCH) {
        for (int l = 0; l < 64; ++l) {
          float vj = __shfl(sv[q], l, 64);
          int   cj = __shfl(cc[q], l, 64);
          #pragma unroll
          for (int p = 0; p < 8; ++p)
            rk[p] += (vj > sv[p] || (vj == sv[p] && cj < cc[p])) ? 1 : 0;
        }
      }
    }
    #pragma unroll
    for (int p = 0; p < 8; ++p) {
      int i = p * 64 + lane;
      if (p < NCH && i < n && rk[p] < TK) idx[(size_t)row * TK + rk[p]] = cc[p];
    }
  }
}

// ---------------- overflow insurance: exact full-row scan for rows with
// cnt > CAP (statistically never taken; all blocks early-exit otherwise)
__global__ __launch_bounds__(256) void k_exact_of(const float* __restrict__ x,
    const int* __restrict__ cnt, int* __restrict__ idx) {
  int lane = threadIdx.x & 63, wid = threadIdx.x >> 6;
  int row = blockIdx.x * 4 + wid;
  if (cnt[row] <= CAP) return;
  const f4* a4 = (const f4*)&x[(size_t)row * DK];
  float bv[16]; int bc[16];
  #pragma unroll
  for (int i = 0; i < 16; ++i) { bv[i] = -3.0e38f; bc[i] = 0x7fffffff; }
  for (int c = lane; c < BN; c += 64) {
    const f4* b4 = (const f4*)&x[(size_t)c * DK];
    float s = 0.f;
    #pragma unroll
    for (int k = 0; k < 32; ++k) {
      f4 a = a4[k], b = b4[k];
      s = fmaf(a.x, b.x, s); s = fmaf(a.y, b.y, s);
      s = fmaf(a.z, b.z, s); s = fmaf(a.w, b.w, s);
    }
    if (s > bv[15] || (s == bv[15] && c < bc[15])) {
      bv[15] = s; bc[15] = c;
      #pragma unroll
      for (int i = 15; i > 0; --i) {
        bool sw = bv[i] > bv[i-1] || (bv[i] == bv[i-1] && bc[i] < bc[i-1]);
        if (sw) {
          float tv = bv[i]; bv[i] = bv[i-1]; bv[i-1] = tv;
          int tc = bc[i]; bc[i] = bc[i-1]; bc[i-1] = tc;
        }
      }
    }
  }
  for (int t = 0; t < TK; ++t) {
    float mv = bv[0]; int mc = bc[0];
    #pragma unroll
    for (int w = 1; w < 64; w <<= 1) {
      float ov = __shfl_xor(mv, w, 64);
      int   oc = __shfl_xor(mc, w, 64);
      if (ov > mv || (ov == mv && oc < mc)) { mv = ov; mc = oc; }
    }
    if (bv[0] == mv && bc[0] == mc) {
      idx[(size_t)row * TK + t] = mc;
      #pragma unroll
      for (int i = 0; i < 15; ++i) { bv[i] = bv[i+1]; bc[i] = bc[i+1]; }
      bv[15] = -3.0e38f; bc[15] = 0x7fffffff;
    }
  }
}

// ================= OLD fallback pipeline (round-3, passing) =================
__global__ __launch_bounds__(256) void k_sim(const float* __restrict__ x,
    int* __restrict__ candC) {
  __shared__ __align__(16) float At[DK][RPB];
  __shared__ __align__(16) float Bt[CT][DK];
  int tid = threadIdx.x;
  int rowblk = blockIdx.x & 255;
  int strip  = blockIdx.x >> 8;
  int r0 = rowblk * RPB;
  int tx = tid & 15, ty = tid >> 4;
  int lane = tid & 63;
  int gbase = lane & 48;
  for (int i = 0; i < 8; ++i) {
    int s = tid + i * 256;
    int r = s >> 5, kq = s & 31;
    f4 v = *(const f4*)&x[(size_t)(r0 + r) * DK + kq * 4];
    At[kq*4+0][r] = v.x; At[kq*4+1][r] = v.y;
    At[kq*4+2][r] = v.z; At[kq*4+3][r] = v.w;
  }
  float listV[4]; int listC[4];
  #pragma unroll
  for (int rr = 0; rr < 4; ++rr) { listV[rr] = -3.0e38f; listC[rr] = 0; }
  __syncthreads();
  for (int ct = 0; ct < SCOLS / CT; ++ct) {
    int c0 = strip * SCOLS + ct * CT;
    for (int i = 0; i < 8; ++i) {
      int s = tid + i * 256;
      int c = s >> 5, kq = s & 31;
      f4 v = *(const f4*)&x[(size_t)(c0 + c) * DK + kq * 4];
      ((f4*)&Bt[c][0])[kq ^ (c & 7)] = v;
    }
    __syncthreads();
    float acc[4][4];
    #pragma unroll
    for (int a = 0; a < 4; ++a)
      #pragma unroll
      for (int b = 0; b < 4; ++b) acc[a][b] = 0.f;
    #pragma unroll 2
    for (int k4 = 0; k4 < 32; ++k4) {
      float ta[4][4], tb[4][4];
      #pragma unroll
      for (int j = 0; j < 4; ++j)
        *(f4*)&ta[j][0] = *(const f4*)&At[k4*4 + j][ty*4];
      #pragma unroll
      for (int jj = 0; jj < 4; ++jj) {
        int c = tx + 16*jj;
        *(f4*)&tb[jj][0] = ((const f4*)&Bt[c][0])[k4 ^ (c & 7)];
      }
      #pragma unroll
      for (int rr = 0; rr < 4; ++rr)
        #pragma unroll
        for (int jj = 0; jj < 4; ++jj)
          acc[rr][jj] += ta[0][rr]*tb[jj][0] + ta[1][rr]*tb[jj][1]
                       + ta[2][rr]*tb[jj][2] + ta[3][rr]*tb[jj][3];
    }
    float tau[4];
    #pragma unroll
    for (int rr = 0; rr < 4; ++rr) tau[rr] = __shfl(listV[rr], 15, 16);
    #pragma unroll
    for (int rr = 0; rr < 4; ++rr) {
      #pragma unroll
      for (int jj = 0; jj < 4; ++jj) {
        float v = acc[rr][jj];
        unsigned long long bal = __ballot(v > tau[rr]);
        unsigned bits = (unsigned)((bal >> gbase) & 0xffffULL);
        while (bits) {
          int l = __ffs(bits) - 1;
          float vb = __shfl(v, l, 16);
          int colb = c0 + l + 16*jj;
          unsigned long long g2 = __ballot(listV[rr] > vb);
          int cnt2 = __popc((unsigned)((g2 >> gbase) & 0xffffULL));
          float sV = __shfl_up(listV[rr], 1, 16);
          int   sC = __shfl_up(listC[rr], 1, 16);
          if (tx == cnt2)      { listV[rr] = vb; listC[rr] = colb; }
          else if (tx > cnt2)  { listV[rr] = sV; listC[rr] = sC; }
          bits &= bits - 1;
        }
      }
    }
    __syncthreads();
  }
  #pragma unroll
  for (int rr = 0; rr < 4; ++rr) {
    int row = r0 + ty * 4 + rr;
    candC[row * (NSTRIP * TK) + strip * TK + tx] = listC[rr];
  }
}

__global__ __launch_bounds__(256) void k_rescore(const float* __restrict__ x,
    const int* __restrict__ candC, int* __restrict__ idx) {
  int lane = threadIdx.x & 63;
  int wid  = threadIdx.x >> 6;
  int half = lane >> 5;
  int ci   = lane & 31;
  int row  = (blockIdx.x * 4 + wid) * 2 + half;
  int col  = candC[row * (NSTRIP * TK) + ci];
  const f4* a4 = (const f4*)&x[(size_t)row * DK];
  const f4* b4 = (const f4*)&x[(size_t)col * DK];
  float s = 0.f;
  #pragma unroll
  for (int k = 0; k < 32; ++k) {
    f4 a = a4[k], b = b4[k];
    s = fmaf(a.x, b.x, s);
    s = fmaf(a.y, b.y, s);
    s = fmaf(a.z, b.z, s);
    s = fmaf(a.w, b.w, s);
  }
  int rank = 0;
  #pragma unroll
  for (int j = 0; j < 32; ++j) {
    float vj = __shfl(s, j, 32);
    int   cj = __shfl(col, j, 32);
    if (vj > s || (vj == s && cj < col)) rank++;
  }
  if (rank < TK) idx[row * TK + rank] = col;
}
// ================= end old fallback =================

// ---------------- CSR by dst: count, scan, fill
__global__ __launch_bounds__(256) void k_count(const int* __restrict__ idx,
                                               int* __restrict__ deg) {
  int i = blockIdx.x * 256 + threadIdx.x;
  int b = i >> 4;
  int t = idx[i];
  if (t != b) atomicAdd(&deg[t], 1);
}

__global__ __launch_bounds__(1024) void k_scan(const int* __restrict__ deg,
                                               int* __restrict__ off) {
  __shared__ int sdat[1024];
  int tid = threadIdx.x;
  int carry = 0;
  for (int ch = 0; ch < BN / 1024; ++ch) {
    int i = ch * 1024 + tid;
    int v = deg[i];
    sdat[tid] = v;
    __syncthreads();
    for (int o = 1; o < 1024; o <<= 1) {
      int t = (tid >= o) ? sdat[tid - o] : 0;
      __syncthreads();
      sdat[tid] += t;
      __syncthreads();
    }
    off[i] = sdat[tid] - v + carry;
    int tot = sdat[1023];
    __syncthreads();
    carry += tot;
  }
  if (tid == 0) off[BN] = carry;
}

__global__ __launch_bounds__(256) void k_fill(const int* __restrict__ idx,
    const int* __restrict__ off, int* __restrict__ cur, int* __restrict__ csr) {
  int i = blockIdx.x * 256 + threadIdx.x;
  if (i >= BN * (TK + 1)) return;
  int b = i / (TK + 1);
  int j = i - b * (TK + 1);
  int t;
  if (j < TK) { t = idx[b * TK + j]; if (t == b) return; }
  else t = b;
  int p = atomicAdd(&cur[t], 1);
  csr[off[t] + p] = b;
}

// ---------------- per-dst online segment softmax + aggregation
__global__ __launch_bounds__(256) void k_aggr(const float* __restrict__ xl,
    const float* __restrict__ xr, const float* __restrict__ att,
    const float* __restrict__ bias, const int* __restrict__ off,
    const int* __restrict__ csr, float* __restrict__ out) {
  int t = blockIdx.x;
  int tid = threadIdx.x;
  int o0 = off[t], o1 = off[t + 1];
  float xrv = xr[(size_t)t * HC + tid];
  float av = att[tid];
  float m = -3.0e38f, den = 0.f, acc = 0.f;
  for (int e = o0; e < o1; ++e) {
    int s = csr[e];
    float xlv = xl[(size_t)s * HC + tid];
    float z = xlv + xrv;
    z = (z > 0.f) ? z : 0.2f * z;
    float sc = z * av;
    #pragma unroll
    for (int w = 1; w < 64; w <<= 1) sc += __shfl_xor(sc, w, 64);
    if (sc > m) {
      float r = __expf(m - sc);
      den *= r; acc *= r; m = sc;
    }
    float p = __expf(sc - m);
    den += p;
    acc += p * xlv;
  }
  out[(size_t)t * HC + tid] = acc / den + bias[tid];
}

extern "C" void kernel_launch(void* const* d_in, const int* in_sizes, int n_in,
                              void* d_out, int out_size, void* d_ws, size_t ws_size,
                              hipStream_t stream) {
  const float* x   = (const float*)d_in[0];
  const float* Wl  = (const float*)d_in[1];
  const float* bl  = (const float*)d_in[2];
  const float* Wr  = (const float*)d_in[3];
  const float* br  = (const float*)d_in[4];
  const float* att = (const float*)d_in[5];
  const float* bias= (const float*)d_in[6];
  float* out = (float*)d_out;

  // ---- new-path workspace layout (~75 MB) + optional score buffer (32 MB)
  const size_t need =
      (size_t)BN*HC*4*2          // xl, xr
    + (size_t)BN*DK*2            // xbf
    + (size_t)BN*16*4            // gmaxu
    + (size_t)BN*4               // tau_u
    + (size_t)BN*4               // cnt
    + (size_t)BN*CAP*4           // cand
    + (size_t)BN*TK*4            // idx
    + (size_t)BN*4*3 + 64        // deg, cur, off(+1)
    + (size_t)BN*(TK+1)*4;       // csr
  const size_t need2 = need + (size_t)BN*CAP*4;   // + svbuf (two-phase exact)

  if (ws_size >= need) {
    char* p = (char*)d_ws;
    float* xl = (float*)p;                    p += (size_t)BN*HC*4;
    float* xr = (float*)p;                    p += (size_t)BN*HC*4;
    unsigned short* xbf = (unsigned short*)p; p += (size_t)BN*DK*2;
    unsigned* gmaxu = (unsigned*)p;           p += (size_t)BN*16*4;
    unsigned* tau_u = (unsigned*)p;           p += (size_t)BN*4;
    int* cnt = (int*)p;                       p += (size_t)BN*4;
    int* cand = (int*)p;                      p += (size_t)BN*CAP*4;
    int* idx = (int*)p;                       p += (size_t)BN*TK*4;
    int* deg = (int*)p;                       p += (size_t)BN*4;
    int* off = (int*)p;                       p += (size_t)(BN+1)*4 + 60;
    int* cur = (int*)p;                       p += (size_t)BN*4;
    int* csr = (int*)p;                       p += (size_t)BN*(TK+1)*4;
    float* svbuf = (float*)p;                 // valid only if ws_size >= need2

    hipLaunchKernelGGL(k_init, dim3(BN*16/256), dim3(256), 0, stream,
                       deg, cur, gmaxu);
    hipLaunchKernelGGL(k_lin,  dim3(BN/16),  dim3(256), 0, stream,
                       x, Wl, bl, Wr, br, xl, xr);
    hipLaunchKernelGGL(k_cvt,  dim3(BN*DK/(256*8)), dim3(256), 0, stream, x, xbf);
    hipLaunchKernelGGL((k_gemm_t<0>), dim3(GSPLIT, BN/128), dim3(512), 0, stream,
                       xbf, gmaxu, (const unsigned*)nullptr,
                       (int*)nullptr, (int*)nullptr);
    hipLaunchKernelGGL(k_tau,  dim3(BN/256), dim3(256), 0, stream,
                       gmaxu, tau_u, cnt);
    hipLaunchKernelGGL((k_gemm_t<1>), dim3(GSPLIT, BN/128), dim3(512), 0, stream,
                       xbf, (unsigned*)nullptr, tau_u, cnt, cand);
    if (ws_size >= need2) {
      // two-phase exact rescore (high-TLP score pass + light rank pass)
      hipLaunchKernelGGL(k_score, dim3(BN), dim3(512), 0, stream,
                         x, cand, cnt, svbuf);
      hipLaunchKernelGGL(k_rank,  dim3(BN/4), dim3(256), 0, stream,
                         svbuf, cand, cnt, idx);
    } else {
      // tier-2: round-13 measured combined kernel (228 us)
      hipLaunchKernelGGL(k_exact, dim3(BN/4), dim3(256), 0, stream,
                         x, cand, cnt, idx);
    }
    hipLaunchKernelGGL(k_exact_of, dim3(BN/4), dim3(256), 0, stream,
                       x, cnt, idx);
    hipLaunchKernelGGL(k_count, dim3(BN*TK/256), dim3(256), 0, stream, idx, deg);
    hipLaunchKernelGGL(k_scan,  dim3(1), dim3(1024), 0, stream, deg, off);
    hipLaunchKernelGGL(k_fill,  dim3((BN*(TK+1))/256), dim3(256), 0, stream,
                       idx, off, cur, csr);
    hipLaunchKernelGGL(k_aggr,  dim3(BN), dim3(256), 0, stream,
                       xl, xr, att, bias, off, csr, out);
  } else {
    // ---- fallback: round-3 passing pipeline (~40 MB)
    float* xl    = (float*)d_ws;
    float* xr    = xl + (size_t)BN * HC;
    int* candC   = (int*)(xr + (size_t)BN * HC);
    int* idx     = candC + (size_t)BN * NSTRIP * TK;
    int* deg     = idx + (size_t)BN * TK;
    int* off     = deg + BN;
    int* cur     = off + (BN + 1);
    int* csr     = cur + BN;
    unsigned* gmaxu_dummy = (unsigned*)(csr + (size_t)BN * (TK + 1));

    hipLaunchKernelGGL(k_init,  dim3(BN/256), dim3(256), 0, stream,
                       deg, cur, gmaxu_dummy);
    hipLaunchKernelGGL(k_lin,   dim3(BN/16),  dim3(256), 0, stream,
                       x, Wl, bl, Wr, br, xl, xr);
    hipLaunchKernelGGL(k_sim,   dim3(NSTRIP*(BN/RPB)), dim3(256), 0, stream,
                       x, candC);
    hipLaunchKernelGGL(k_rescore, dim3(BN/8), dim3(256), 0, stream,
                       x, candC, idx);
    hipLaunchKernelGGL(k_count, dim3(BN*TK/256), dim3(256), 0, stream, idx, deg);
    hipLaunchKernelGGL(k_scan,  dim3(1), dim3(1024), 0, stream, deg, off);
    hipLaunchKernelGGL(k_fill,  dim3((BN*(TK+1))/256), dim3(256), 0, stream,
                       idx, off, cur, csr);
    hipLaunchKernelGGL(k_aggr,  dim3(BN), dim3(256), 0, stream,
                       xl, xr, att, bias, off, csr, out);
  }
}

// Round 20
// 632.226 us; speedup vs baseline: 1.0608x; 1.0203x over previous
//
#include <hip/hip_runtime.h>
#include <math.h>

// Problem constants (fixed by the reference; k input is ignored, always 16)
#define BN 16384
#define DK 128
#define HN 4
#define CN 64
#define HC 256
#define TK 16
#define CAP 512              // candidate buffer capacity per row

// ---- streamed GEMM geometry: 128-row panel x 1024-col strip per block
#define GSPLIT 16            // column strips
#define GSPAN  1024          // cols per strip (= one gmax group)
#define GBC    128           // cols per B tile (32 KB)
#define GNT    (GSPAN / GBC) // 8 steps per strip

// ---- old fallback pipeline geometry
#define NSTRIP 2
#define SCOLS (BN / NSTRIP)
#define RPB 64
#define CT 64

typedef float4 f4;
typedef __attribute__((ext_vector_type(8))) short short8;
typedef __attribute__((ext_vector_type(4))) float f32x4;

__device__ __forceinline__ unsigned bf_rne(float f) {
  unsigned u = __float_as_uint(f);
  u += 0x7fffu + ((u >> 16) & 1u);
  return u >> 16;
}

// order-preserving float->uint map (monotone for all finite floats)
__device__ __forceinline__ unsigned fmap(float f) {
  unsigned b = __float_as_uint(f);
  return (b & 0x80000000u) ? ~b : (b | 0x80000000u);
}

// async global->LDS, 16B per lane (dest is wave-uniform base + lane*16)
__device__ __forceinline__ void gload16(const unsigned short* g,
                                        unsigned short* l) {
  __builtin_amdgcn_global_load_lds(
      (const __attribute__((address_space(1))) unsigned int*)g,
      (__attribute__((address_space(3))) unsigned int*)l, 16, 0, 0);
}

// ---------------- init: deg=1, cur=0, gmaxu=0 (re-init every call)
__global__ __launch_bounds__(256) void k_init(int* deg, int* cur,
                                              unsigned* gmaxu) {
  int i = blockIdx.x * 256 + threadIdx.x;
  if (i < BN) { deg[i] = 1; cur[i] = 0; }
  if (i < BN * 16) gmaxu[i] = 0u;    // mapped ~ -inf
}

// ---------------- x_l = x@W_l + b_l ; x_r = x@W_r + b_r  (fp32, 16 rows/block)
__global__ __launch_bounds__(256) void k_lin(const float* __restrict__ x,
    const float* __restrict__ Wl, const float* __restrict__ bl,
    const float* __restrict__ Wr, const float* __restrict__ br,
    float* __restrict__ xl, float* __restrict__ xr) {
  __shared__ __align__(16) float xst[DK][16];
  int tid = threadIdx.x;
  int r0 = blockIdx.x * 16;
  for (int i = 0; i < 2; ++i) {
    int s = tid + i * 256;
    int r = s >> 5, kq = s & 31;
    f4 v = *(const f4*)&x[(size_t)(r0 + r) * DK + kq * 4];
    xst[kq*4+0][r] = v.x; xst[kq*4+1][r] = v.y;
    xst[kq*4+2][r] = v.z; xst[kq*4+3][r] = v.w;
  }
  __syncthreads();
  float al[16], ar[16];
  #pragma unroll
  for (int r = 0; r < 16; ++r) { al[r] = 0.f; ar[r] = 0.f; }
  for (int k = 0; k < DK; ++k) {
    float wl = Wl[k * HC + tid];
    float wr = Wr[k * HC + tid];
    float xv[16];
    *(f4*)&xv[0]  = *(const f4*)&xst[k][0];
    *(f4*)&xv[4]  = *(const f4*)&xst[k][4];
    *(f4*)&xv[8]  = *(const f4*)&xst[k][8];
    *(f4*)&xv[12] = *(const f4*)&xst[k][12];
    #pragma unroll
    for (int r = 0; r < 16; ++r) { al[r] += xv[r] * wl; ar[r] += xv[r] * wr; }
  }
  float bbl = bl[tid], bbr = br[tid];
  #pragma unroll
  for (int r = 0; r < 16; ++r) {
    xl[(size_t)(r0 + r) * HC + tid] = al[r] + bbl;
    xr[(size_t)(r0 + r) * HC + tid] = ar[r] + bbr;
  }
}

// ---------------- x (fp32) -> x_bf (bf16, RNE)
__global__ __launch_bounds__(256) void k_cvt(const float* __restrict__ x,
                                             unsigned short* __restrict__ xbf) {
  size_t base = (size_t)(blockIdx.x * 256 + threadIdx.x) * 8;
  f4 a = *(const f4*)&x[base];
  f4 b = *(const f4*)&x[base + 4];
  uint4 o;
  o.x = bf_rne(a.x) | (bf_rne(a.y) << 16);
  o.y = bf_rne(a.z) | (bf_rne(a.w) << 16);
  o.z = bf_rne(b.x) | (bf_rne(b.y) << 16);
  o.w = bf_rne(b.z) | (bf_rne(b.w) << 16);
  *(uint4*)&xbf[base] = o;
}

// ---------------- streamed MFMA scorer: round-19 form (measured 170 us,
// VGPR 88, bank conflicts 12.6M->8.9M, no scratch). ROUND-20 CHANGE: hoist
// ALL FOUR A-fragments (af4[4][4], 64 regs, read once per tile) — VGPR was
// still 88 after the af2 hoist, so ~40 regs of headroom remain below the
// 128 cliff. A-side LDS reads drop 64->16 per wave/tile (only B's 32/tile
// remain in-loop). Expected live set ~115 VGPR + 32 AGPR (lighter than
// round-14's spilling variant: bfr now per-ks, MODE-1 de-unrolled via hmL).
// Go/no-go: WRITE_SIZE balloons => allocator tipped => revert.
// Scores bitwise identical: same LDS bytes, same ks-ascending MFMA chain;
// both MODEs transformed identically.
// Per block: 128-row panel vs 1024-col strip, 8 steps of 128 cols, 8 waves
// (2x4 of 64x32 tiles). B tiles double-buffered with global_load_lds issued
// before compute, one __syncthreads per step.
// acc[m][n][r]: row = q0+64wm+16m+4th+r, col = c0+128t+32wn+16n+tq.
// MODE 0: runtime loop, lane-local running max, block-end reduce.
// MODE 1: runtime loop, hit masks in LDS (hmL[t][tid], own-slot only),
// atomicAdd+store flush AFTER the loop.
template <int MODE>
__global__ __launch_bounds__(512, 1) void k_gemm_t(
    const unsigned short* __restrict__ xbf, unsigned* __restrict__ gmaxu,
    const unsigned* __restrict__ tau_u, int* __restrict__ cnt,
    int* __restrict__ cand) {
  __shared__ __align__(16) unsigned short As[128 * DK];
  __shared__ __align__(16) unsigned short Bs0[128 * DK];
  __shared__ __align__(16) unsigned short Bs1[128 * DK];
  __shared__ float red[4][128];
  int tid = threadIdx.x;
  int q0 = blockIdx.y * 128;
  int c0 = blockIdx.x * GSPAN;
  int lane = tid & 63;
  int wid = tid >> 6;
  int wm = wid & 1, wn = wid >> 1;
  int tq = lane & 15, th = lane >> 4;

  // t-invariant staging geometry: slot = tid + i*512 -> (row, 16B chunk)
  // source chunk pre-swizzled so linear LDS dest == XOR-swizzled layout
  int soff[4];       // element offset within a 128-row tile
  #pragma unroll
  for (int i = 0; i < 4; ++i) {
    int slot = tid + i * 512;
    int row = slot >> 4, c8 = slot & 15;
    soff[i] = row * DK + ((c8 ^ (row & 7)) * 8);
  }
  // prologue: stage A panel + B tile 0
  #pragma unroll
  for (int i = 0; i < 4; ++i)
    gload16(&xbf[(size_t)q0 * DK + soff[i]], &As[(tid + i * 512) * 8]);
  #pragma unroll
  for (int i = 0; i < 4; ++i)
    gload16(&xbf[(size_t)c0 * DK + soff[i]], &Bs0[(tid + i * 512) * 8]);
  __syncthreads();   // drains vmcnt -> A and B0 resident

  // full A-fragment hoist: all m pinned in registers for all steps
  short8 af4[4][4];
  #pragma unroll
  for (int m = 0; m < 4; ++m) {
    int ra = 64 * wm + 16 * m + tq;
    #pragma unroll
    for (int ks = 0; ks < 4; ++ks)
      af4[m][ks] = *(const short8*)&As[ra * DK +
                       (((ks*4+th) ^ (ra & 7)) * 8)];
  }

  float gmx[4][4];   // MODE 0: lane-local running max
  float tauf[4][4];  // MODE 1: float-domain threshold
  if constexpr (MODE == 0) {
    #pragma unroll
    for (int m = 0; m < 4; ++m)
      #pragma unroll
      for (int r = 0; r < 4; ++r) gmx[m][r] = -3.0e38f;
  } else {
    #pragma unroll
    for (int m = 0; m < 4; ++m)
      #pragma unroll
      for (int r = 0; r < 4; ++r) {
        unsigned tu = tau_u[q0 + 64*wm + 16*m + 4*th + r];
        tauf[m][r] = __uint_as_float(
            (tu >= 0x80000000u) ? (tu ^ 0x80000000u) : ~tu);
      }
  }

  if constexpr (MODE == 0) {
    // ---- runtime loop (round-19 schedule; all A hoisted, B per-ks)
    unsigned short* Bc = Bs0;
    unsigned short* Bn = Bs1;
    for (int t = 0; t < GNT; ++t) {
      if (t + 1 < GNT) {
        size_t gb = (size_t)(c0 + (t + 1) * GBC) * DK;
        #pragma unroll
        for (int i = 0; i < 4; ++i)
          gload16(&xbf[gb + soff[i]], &Bn[(tid + i * 512) * 8]);
      }
      f32x4 acc[4][2];
      #pragma unroll
      for (int m = 0; m < 4; ++m)
        #pragma unroll
        for (int n = 0; n < 2; ++n) {
          acc[m][n][0] = 0.f; acc[m][n][1] = 0.f;
          acc[m][n][2] = 0.f; acc[m][n][3] = 0.f;
        }
      #pragma unroll
      for (int ks = 0; ks < 4; ++ks) {
        short8 bfq[2];
        #pragma unroll
        for (int n = 0; n < 2; ++n) {
          int rb = 32 * wn + 16 * n + tq;
          bfq[n] = *(const short8*)&Bc[rb * DK +
                       (((ks*4+th) ^ (rb & 7)) * 8)];
        }
        #pragma unroll
        for (int m = 0; m < 4; ++m)
          #pragma unroll
          for (int n = 0; n < 2; ++n)
            acc[m][n] = __builtin_amdgcn_mfma_f32_16x16x32_bf16(
                af4[m][ks], bfq[n], acc[m][n], 0, 0, 0);
      }
      #pragma unroll
      for (int m = 0; m < 4; ++m)
        #pragma unroll
        for (int r = 0; r < 4; ++r)
          gmx[m][r] = fmaxf(gmx[m][r], fmaxf(acc[m][0][r], acc[m][1][r]));
      __syncthreads();
      unsigned short* tb = Bc; Bc = Bn; Bn = tb;
    }
    // reduce over tq lanes, then across wn waves via LDS; plain store
    #pragma unroll
    for (int m = 0; m < 4; ++m)
      #pragma unroll
      for (int r = 0; r < 4; ++r) {
        float v = gmx[m][r];
        #pragma unroll
        for (int w = 1; w < 16; w <<= 1) v = fmaxf(v, __shfl_xor(v, w, 64));
        if (tq == 0) red[wn][64*wm + 16*m + 4*th + r] = v;
      }
    __syncthreads();
    if (tid < 128) {
      float v = fmaxf(fmaxf(red[0][tid], red[1][tid]),
                      fmaxf(red[2][tid], red[3][tid]));
      gmaxu[(q0 + tid) * 16 + blockIdx.x] = fmap(v);
    }
  } else {
    // ---- runtime loop with hit masks in LDS (own-slot only, no extra sync)
    __shared__ unsigned hmL[GNT][512];
    unsigned short* Bc = Bs0;
    unsigned short* Bn = Bs1;
    for (int t = 0; t < GNT; ++t) {
      if (t + 1 < GNT) {
        size_t gb = (size_t)(c0 + (t + 1) * GBC) * DK;
        #pragma unroll
        for (int i = 0; i < 4; ++i)
          gload16(&xbf[gb + soff[i]], &Bn[(tid + i * 512) * 8]);
      }
      f32x4 acc[4][2];
      #pragma unroll
      for (int m = 0; m < 4; ++m)
        #pragma unroll
        for (int n = 0; n < 2; ++n) {
          acc[m][n][0] = 0.f; acc[m][n][1] = 0.f;
          acc[m][n][2] = 0.f; acc[m][n][3] = 0.f;
        }
      #pragma unroll
      for (int ks = 0; ks < 4; ++ks) {
        short8 bfq[2];
        #pragma unroll
        for (int n = 0; n < 2; ++n) {
          int rb = 32 * wn + 16 * n + tq;
          bfq[n] = *(const short8*)&Bc[rb * DK +
                       (((ks*4+th) ^ (rb & 7)) * 8)];
        }
        #pragma unroll
        for (int m = 0; m < 4; ++m)
          #pragma unroll
          for (int n = 0; n < 2; ++n)
            acc[m][n] = __builtin_amdgcn_mfma_f32_16x16x32_bf16(
                af4[m][ks], bfq[n], acc[m][n], 0, 0, 0);
      }
      unsigned mm = 0;
      #pragma unroll
      for (int m = 0; m < 4; ++m)
        #pragma unroll
        for (int r = 0; r < 4; ++r)
          #pragma unroll
          for (int n = 0; n < 2; ++n)
            mm |= (acc[m][n][r] >= tauf[m][r])
                      ? (1u << ((m << 3) | (r << 1) | n)) : 0u;
      hmL[t][tid] = mm;
      __syncthreads();
      unsigned short* tb = Bc; Bc = Bn; Bn = tb;
    }
    // deferred candidate flush: atomics OUTSIDE the pipelined loop.
    // Same set as inline (same compares), order changes only.
    for (int t = 0; t < GNT; ++t) {
      unsigned mm = hmL[t][tid];
      while (mm) {
        int b = __ffs(mm) - 1;
        mm &= mm - 1;
        int m = b >> 3, r = (b >> 1) & 3, n = b & 1;
        int row = q0 + 64*wm + 16*m + 4*th + r;
        int col = c0 + t * GBC + 32*wn + 16*n + tq;
        int slot = atomicAdd(&cnt[row], 1);
        if (slot < CAP) cand[(size_t)row * CAP + slot] = col;
      }
    }
  }
}

// ---------------- tau = min of 16 group maxes (<= true 16th value, provably);
// also zero candidate counters
__global__ __launch_bounds__(256) void k_tau(const unsigned* __restrict__ gmaxu,
    unsigned* __restrict__ tau_u, int* __restrict__ cnt) {
  int row = blockIdx.x * 256 + threadIdx.x;
  unsigned t = 0xFFFFFFFFu;
  #pragma unroll
  for (int g = 0; g < 16; ++g) t = min(t, gmaxu[row * 16 + g]);
  tau_u[row] = t;
  cnt[row] = 0;
}

// ---------------- TWO-PHASE exact rescore (used when workspace allows the
// +32 MB score buffer). Splits score (needs pre[8]/fmaf chains) from rank
// (needs sv/cc/rk arrays) so NEITHER kernel carries the union register set.
// Round-14 measured: both below the top-5 cutoff.
// PHASE A: one block per row, 512 threads, one candidate per thread.
// Dot = sequential fmaf chain (round-3-proven exact match vs the reference;
// summation order MUST NOT change). (512,4) caps VGPR at 128 (under cliff).
__global__ __launch_bounds__(512, 4) void k_score(const float* __restrict__ x,
    const int* __restrict__ cand, const int* __restrict__ cnt,
    float* __restrict__ svbuf) {
  __shared__ __align__(16) float arow[DK];
  int row = blockIdx.x;
  int i = threadIdx.x;
  int n = cnt[row];
  if (i < 32)
    *(f4*)&arow[i * 4] = *(const f4*)&x[(size_t)row * DK + i * 4];
  __syncthreads();
  if (n > CAP || i >= n) return;     // overflow rows: k_exact_of
  const f4* as = (const f4*)arow;
  int col = cand[(size_t)row * CAP + i];
  const f4* b4 = (const f4*)&x[(size_t)col * DK];
  f4 pre[8];
  #pragma unroll
  for (int q = 0; q < 8; ++q) pre[q] = b4[q * 4];     // one load per 64B line
  float t = 0.f;
  #pragma unroll
  for (int k = 0; k < 32; ++k) {
    f4 a = as[k];
    f4 b = ((k & 3) == 0) ? pre[k >> 2] : b4[k];      // static select (unroll)
    t = fmaf(a.x, b.x, t); t = fmaf(a.y, b.y, t);
    t = fmaf(a.z, b.z, t); t = fmaf(a.w, b.w, t);
  }
  svbuf[(size_t)row * CAP + i] = t;
}

// PHASE B: one wave per row; coalesced score/col loads; chunked broadcast
// rank with the SAME sentinels and (value desc, col asc) comparison as the
// proven combined kernel -> bitwise-identical idx. ~24-reg arrays + temps,
// under the 128 cliff, no spills.
__global__ __launch_bounds__(256) void k_rank(const float* __restrict__ svbuf,
    const int* __restrict__ cand, const int* __restrict__ cnt,
    int* __restrict__ idx) {
  int lane = threadIdx.x & 63, wid = threadIdx.x >> 6;
  int row = blockIdx.x * 4 + wid;
  int n = cnt[row];
  if (n > CAP) return;               // k_exact_of covers this row
  int NCH = (n + 63) >> 6;
  float sv[8]; int cc[8]; int rk[8];
  #pragma unroll
  for (int p = 0; p < 8; ++p) {
    sv[p] = -3.0e38f; cc[p] = 0x7fffffff; rk[p] = 0;
  }
  #pragma unroll
  for (int p = 0; p < 8; ++p) {
    if (p < NCH) {
      int i = p * 64 + lane;
      if (i < n) {
        sv[p] = svbuf[(size_t)row * CAP + i];
        cc[p] = cand[(size_t)row * CAP + i];
      }
    }
  }
  #pragma unroll
  for (int q = 0; q < 8; ++q) {
    if (q < NCH) {
      for (int l = 0; l < 64; ++l) {
        float vj = __shfl(sv[q], l, 64);
        int   cj = __shfl(cc[q], l, 64);
        #pragma unroll
        for (int p = 0; p < 8; ++p)
          rk[p] += (vj > sv[p] || (vj == sv[p] && cj < cc[p])) ? 1 : 0;
      }
    }
  }
  #pragma unroll
  for (int p = 0; p < 8; ++p) {
    int i = p * 64 + lane;
    if (p < NCH && i < n && rk[p] < TK) idx[(size_t)row * TK + rk[p]] = cc[p];
  }
}

// ---------------- exact fp32-chain rescore of candidates -> top-16 (TIER-2:
// used when workspace lacks the score buffer; round-13 measured 228 us).
__global__ __launch_bounds__(256, 4) void k_exact(const float* __restrict__ x,
    const int* __restrict__ cand, const int* __restrict__ cnt,
    int* __restrict__ idx) {
  __shared__ __align__(16) float arow[4][DK];
  int lane = threadIdx.x & 63, wid = threadIdx.x >> 6;
  int row = blockIdx.x * 4 + wid;
  int n = cnt[row];
  // stage this wave's query row into LDS (all later reads are broadcasts)
  if (lane < 32)
    *(f4*)&arow[wid][lane * 4] = *(const f4*)&x[(size_t)row * DK + lane * 4];
  __syncthreads();
  if (n > CAP) return;               // k_exact_of covers this row
  const f4* as = (const f4*)&arow[wid][0];

  if (n <= 64) {
    // ---- fast path: one candidate per lane
    bool ok = lane < n;
    int col = ok ? cand[(size_t)row * CAP + lane] : row;
    const f4* b4 = (const f4*)&x[(size_t)col * DK];
    f4 pre[8];
    #pragma unroll
    for (int q = 0; q < 8; ++q) pre[q] = b4[q * 4];   // one load per 64B line
    float t = 0.f;
    #pragma unroll
    for (int k = 0; k < 32; ++k) {
      f4 a = as[k];
      f4 b = ((k & 3) == 0) ? pre[k >> 2] : b4[k];    // static select (unroll)
      t = fmaf(a.x, b.x, t); t = fmaf(a.y, b.y, t);
      t = fmaf(a.z, b.z, t); t = fmaf(a.w, b.w, t);
    }
    float sv = ok ? t : -3.0e38f;
    int cc = ok ? col : 0x7fffffff;
    int rk = 0;
    for (int l = 0; l < 64; ++l) {
      float vj = __shfl(sv, l, 64);
      int   cj = __shfl(cc, l, 64);
      rk += (vj > sv || (vj == sv && cj < cc)) ? 1 : 0;
    }
    if (ok && rk < TK) idx[(size_t)row * TK + rk] = cc;
  } else {
    // ---- general path (64 < n <= CAP): chunked, same structure
    int NCH = (n + 63) >> 6;
    float sv[8]; int cc[8]; int rk[8];
    #pragma unroll
    for (int p = 0; p < 8; ++p) {
      sv[p] = -3.0e38f; cc[p] = 0x7fffffff; rk[p] = 0;
    }
    #pragma unroll
    for (int p = 0; p < 8; ++p) {
      if (p < NCH) {
        int i = p * 64 + lane;
        bool ok = i < n;
        int col = ok ? cand[(size_t)row * CAP + i] : row;
        const f4* b4 = (const f4*)&x[(size_t)col * DK];
        f4 pre[8];
        #pragma unroll
        for (int q = 0; q < 8; ++q) pre[q] = b4[q * 4];
        float t = 0.f;
        #pragma unroll
        for (int k = 0; k < 32; ++k) {
          f4 a = as[k];
          f4 b = ((k & 3) == 0) ? pre[k >> 2] : b4[k];
          t = fmaf(a.x, b.x, t); t = fmaf(a.y, b.y, t);
          t = fmaf(a.z, b.z, t); t = fmaf(a.w, b.w, t);
        }
        if (ok) { sv[p] = t; cc[p] = col; }
      }
    }
    #pragma unroll
    for (int q = 0; q < 8; ++q) {
      if (q < NCH) {
        for (int l = 0; l < 64; ++l) {
          float vj = __shfl(sv[q], l, 64);
          int   cj = __shfl(cc[q], l, 64);
          #pragma unroll
          for (int p = 0; p < 8; ++p)
            rk[p] += (vj > sv[p] || (vj == sv[p] && cj < cc[p])) ? 1 : 0;
        }
      }
    }
    #pragma unroll
    for (int p = 0; p < 8; ++p) {
      int i = p * 64 + lane;
      if (p < NCH && i < n && rk[p] < TK) idx[(size_t)row * TK + rk[p]] = cc[p];
    }
  }
}

// ---------------- overflow insurance: exact full-row scan for rows with
// cnt > CAP (statistically never taken; all blocks early-exit otherwise)
__global__ __launch_bounds__(256) void k_exact_of(const float* __restrict__ x,
    const int* __restrict__ cnt, int* __restrict__ idx) {
  int lane = threadIdx.x & 63, wid = threadIdx.x >> 6;
  int row = blockIdx.x * 4 + wid;
  if (cnt[row] <= CAP) return;
  const f4* a4 = (const f4*)&x[(size_t)row * DK];
  float bv[16]; int bc[16];
  #pragma unroll
  for (int i = 0; i < 16; ++i) { bv[i] = -3.0e38f; bc[i] = 0x7fffffff; }
  for (int c = lane; c < BN; c += 64) {
    const f4* b4 = (const f4*)&x[(size_t)c * DK];
    float s = 0.f;
    #pragma unroll
    for (int k = 0; k < 32; ++k) {
      f4 a = a4[k], b = b4[k];
      s = fmaf(a.x, b.x, s); s = fmaf(a.y, b.y, s);
      s = fmaf(a.z, b.z, s); s = fmaf(a.w, b.w, s);
    }
    if (s > bv[15] || (s == bv[15] && c < bc[15])) {
      bv[15] = s; bc[15] = c;
      #pragma unroll
      for (int i = 15; i > 0; --i) {
        bool sw = bv[i] > bv[i-1] || (bv[i] == bv[i-1] && bc[i] < bc[i-1]);
        if (sw) {
          float tv = bv[i]; bv[i] = bv[i-1]; bv[i-1] = tv;
          int tc = bc[i]; bc[i] = bc[i-1]; bc[i-1] = tc;
        }
      }
    }
  }
  for (int t = 0; t < TK; ++t) {
    float mv = bv[0]; int mc = bc[0];
    #pragma unroll
    for (int w = 1; w < 64; w <<= 1) {
      float ov = __shfl_xor(mv, w, 64);
      int   oc = __shfl_xor(mc, w, 64);
      if (ov > mv || (ov == mv && oc < mc)) { mv = ov; mc = oc; }
    }
    if (bv[0] == mv && bc[0] == mc) {
      idx[(size_t)row * TK + t] = mc;
      #pragma unroll
      for (int i = 0; i < 15; ++i) { bv[i] = bv[i+1]; bc[i] = bc[i+1]; }
      bv[15] = -3.0e38f; bc[15] = 0x7fffffff;
    }
  }
}

// ================= OLD fallback pipeline (round-3, passing) =================
__global__ __launch_bounds__(256) void k_sim(const float* __restrict__ x,
    int* __restrict__ candC) {
  __shared__ __align__(16) float At[DK][RPB];
  __shared__ __align__(16) float Bt[CT][DK];
  int tid = threadIdx.x;
  int rowblk = blockIdx.x & 255;
  int strip  = blockIdx.x >> 8;
  int r0 = rowblk * RPB;
  int tx = tid & 15, ty = tid >> 4;
  int lane = tid & 63;
  int gbase = lane & 48;
  for (int i = 0; i < 8; ++i) {
    int s = tid + i * 256;
    int r = s >> 5, kq = s & 31;
    f4 v = *(const f4*)&x[(size_t)(r0 + r) * DK + kq * 4];
    At[kq*4+0][r] = v.x; At[kq*4+1][r] = v.y;
    At[kq*4+2][r] = v.z; At[kq*4+3][r] = v.w;
  }
  float listV[4]; int listC[4];
  #pragma unroll
  for (int rr = 0; rr < 4; ++rr) { listV[rr] = -3.0e38f; listC[rr] = 0; }
  __syncthreads();
  for (int ct = 0; ct < SCOLS / CT; ++ct) {
    int c0 = strip * SCOLS + ct * CT;
    for (int i = 0; i < 8; ++i) {
      int s = tid + i * 256;
      int c = s >> 5, kq = s & 31;
      f4 v = *(const f4*)&x[(size_t)(c0 + c) * DK + kq * 4];
      ((f4*)&Bt[c][0])[kq ^ (c & 7)] = v;
    }
    __syncthreads();
    float acc[4][4];
    #pragma unroll
    for (int a = 0; a < 4; ++a)
      #pragma unroll
      for (int b = 0; b < 4; ++b) acc[a][b] = 0.f;
    #pragma unroll 2
    for (int k4 = 0; k4 < 32; ++k4) {
      float ta[4][4], tb[4][4];
      #pragma unroll
      for (int j = 0; j < 4; ++j)
        *(f4*)&ta[j][0] = *(const f4*)&At[k4*4 + j][ty*4];
      #pragma unroll
      for (int jj = 0; jj < 4; ++jj) {
        int c = tx + 16*jj;
        *(f4*)&tb[jj][0] = ((const f4*)&Bt[c][0])[k4 ^ (c & 7)];
      }
      #pragma unroll
      for (int rr = 0; rr < 4; ++rr)
        #pragma unroll
        for (int jj = 0; jj < 4; ++jj)
          acc[rr][jj] += ta[0][rr]*tb[jj][0] + ta[1][rr]*tb[jj][1]
                       + ta[2][rr]*tb[jj][2] + ta[3][rr]*tb[jj][3];
    }
    float tau[4];
    #pragma unroll
    for (int rr = 0; rr < 4; ++rr) tau[rr] = __shfl(listV[rr], 15, 16);
    #pragma unroll
    for (int rr = 0; rr < 4; ++rr) {
      #pragma unroll
      for (int jj = 0; jj < 4; ++jj) {
        float v = acc[rr][jj];
        unsigned long long bal = __ballot(v > tau[rr]);
        unsigned bits = (unsigned)((bal >> gbase) & 0xffffULL);
        while (bits) {
          int l = __ffs(bits) - 1;
          float vb = __shfl(v, l, 16);
          int colb = c0 + l + 16*jj;
          unsigned long long g2 = __ballot(listV[rr] > vb);
          int cnt2 = __popc((unsigned)((g2 >> gbase) & 0xffffULL));
          float sV = __shfl_up(listV[rr], 1, 16);
          int   sC = __shfl_up(listC[rr], 1, 16);
          if (tx == cnt2)      { listV[rr] = vb; listC[rr] = colb; }
          else if (tx > cnt2)  { listV[rr] = sV; listC[rr] = sC; }
          bits &= bits - 1;
        }
      }
    }
    __syncthreads();
  }
  #pragma unroll
  for (int rr = 0; rr < 4; ++rr) {
    int row = r0 + ty * 4 + rr;
    candC[row * (NSTRIP * TK) + strip * TK + tx] = listC[rr];
  }
}

__global__ __launch_bounds__(256) void k_rescore(const float* __restrict__ x,
    const int* __restrict__ candC, int* __restrict__ idx) {
  int lane = threadIdx.x & 63;
  int wid  = threadIdx.x >> 6;
  int half = lane >> 5;
  int ci   = lane & 31;
  int row  = (blockIdx.x * 4 + wid) * 2 + half;
  int col  = candC[row * (NSTRIP * TK) + ci];
  const f4* a4 = (const f4*)&x[(size_t)row * DK];
  const f4* b4 = (const f4*)&x[(size_t)col * DK];
  float s = 0.f;
  #pragma unroll
  for (int k = 0; k < 32; ++k) {
    f4 a = a4[k], b = b4[k];
    s = fmaf(a.x, b.x, s);
    s = fmaf(a.y, b.y, s);
    s = fmaf(a.z, b.z, s);
    s = fmaf(a.w, b.w, s);
  }
  int rank = 0;
  #pragma unroll
  for (int j = 0; j < 32; ++j) {
    float vj = __shfl(s, j, 32);
    int   cj = __shfl(col, j, 32);
    if (vj > s || (vj == s && cj < col)) rank++;
  }
  if (rank < TK) idx[row * TK + rank] = col;
}
// ================= end old fallback =================

// ---------------- CSR by dst: count, scan, fill
__global__ __launch_bounds__(256) void k_count(const int* __restrict__ idx,
                                               int* __restrict__ deg) {
  int i = blockIdx.x * 256 + threadIdx.x;
  int b = i >> 4;
  int t = idx[i];
  if (t != b) atomicAdd(&deg[t], 1);
}

__global__ __launch_bounds__(1024) void k_scan(const int* __restrict__ deg,
                                               int* __restrict__ off) {
  __shared__ int sdat[1024];
  int tid = threadIdx.x;
  int carry = 0;
  for (int ch = 0; ch < BN / 1024; ++ch) {
    int i = ch * 1024 + tid;
    int v = deg[i];
    sdat[tid] = v;
    __syncthreads();
    for (int o = 1; o < 1024; o <<= 1) {
      int t = (tid >= o) ? sdat[tid - o] : 0;
      __syncthreads();
      sdat[tid] += t;
      __syncthreads();
    }
    off[i] = sdat[tid] - v + carry;
    int tot = sdat[1023];
    __syncthreads();
    carry += tot;
  }
  if (tid == 0) off[BN] = carry;
}

__global__ __launch_bounds__(256) void k_fill(const int* __restrict__ idx,
    const int* __restrict__ off, int* __restrict__ cur, int* __restrict__ csr) {
  int i = blockIdx.x * 256 + threadIdx.x;
  if (i >= BN * (TK + 1)) return;
  int b = i / (TK + 1);
  int j = i - b * (TK + 1);
  int t;
  if (j < TK) { t = idx[b * TK + j]; if (t == b) return; }
  else t = b;
  int p = atomicAdd(&cur[t], 1);
  csr[off[t] + p] = b;
}

// ---------------- per-dst online segment softmax + aggregation
__global__ __launch_bounds__(256) void k_aggr(const float* __restrict__ xl,
    const float* __restrict__ xr, const float* __restrict__ att,
    const float* __restrict__ bias, const int* __restrict__ off,
    const int* __restrict__ csr, float* __restrict__ out) {
  int t = blockIdx.x;
  int tid = threadIdx.x;
  int o0 = off[t], o1 = off[t + 1];
  float xrv = xr[(size_t)t * HC + tid];
  float av = att[tid];
  float m = -3.0e38f, den = 0.f, acc = 0.f;
  for (int e = o0; e < o1; ++e) {
    int s = csr[e];
    float xlv = xl[(size_t)s * HC + tid];
    float z = xlv + xrv;
    z = (z > 0.f) ? z : 0.2f * z;
    float sc = z * av;
    #pragma unroll
    for (int w = 1; w < 64; w <<= 1) sc += __shfl_xor(sc, w, 64);
    if (sc > m) {
      float r = __expf(m - sc);
      den *= r; acc *= r; m = sc;
    }
    float p = __expf(sc - m);
    den += p;
    acc += p * xlv;
  }
  out[(size_t)t * HC + tid] = acc / den + bias[tid];
}

extern "C" void kernel_launch(void* const* d_in, const int* in_sizes, int n_in,
                              void* d_out, int out_size, void* d_ws, size_t ws_size,
                              hipStream_t stream) {
  const float* x   = (const float*)d_in[0];
  const float* Wl  = (const float*)d_in[1];
  const float* bl  = (const float*)d_in[2];
  const float* Wr  = (const float*)d_in[3];
  const float* br  = (const float*)d_in[4];
  const float* att = (const float*)d_in[5];
  const float* bias= (const float*)d_in[6];
  float* out = (float*)d_out;

  // ---- new-path workspace layout (~75 MB) + optional score buffer (32 MB)
  const size_t need =
      (size_t)BN*HC*4*2          // xl, xr
    + (size_t)BN*DK*2            // xbf
    + (size_t)BN*16*4            // gmaxu
    + (size_t)BN*4               // tau_u
    + (size_t)BN*4               // cnt
    + (size_t)BN*CAP*4           // cand
    + (size_t)BN*TK*4            // idx
    + (size_t)BN*4*3 + 64        // deg, cur, off(+1)
    + (size_t)BN*(TK+1)*4;       // csr
  const size_t need2 = need + (size_t)BN*CAP*4;   // + svbuf (two-phase exact)

  if (ws_size >= need) {
    char* p = (char*)d_ws;
    float* xl = (float*)p;                    p += (size_t)BN*HC*4;
    float* xr = (float*)p;                    p += (size_t)BN*HC*4;
    unsigned short* xbf = (unsigned short*)p; p += (size_t)BN*DK*2;
    unsigned* gmaxu = (unsigned*)p;           p += (size_t)BN*16*4;
    unsigned* tau_u = (unsigned*)p;           p += (size_t)BN*4;
    int* cnt = (int*)p;                       p += (size_t)BN*4;
    int* cand = (int*)p;                      p += (size_t)BN*CAP*4;
    int* idx = (int*)p;                       p += (size_t)BN*TK*4;
    int* deg = (int*)p;                       p += (size_t)BN*4;
    int* off = (int*)p;                       p += (size_t)(BN+1)*4 + 60;
    int* cur = (int*)p;                       p += (size_t)BN*4;
    int* csr = (int*)p;                       p += (size_t)BN*(TK+1)*4;
    float* svbuf = (float*)p;                 // valid only if ws_size >= need2

    hipLaunchKernelGGL(k_init, dim3(BN*16/256), dim3(256), 0, stream,
                       deg, cur, gmaxu);
    hipLaunchKernelGGL(k_lin,  dim3(BN/16),  dim3(256), 0, stream,
                       x, Wl, bl, Wr, br, xl, xr);
    hipLaunchKernelGGL(k_cvt,  dim3(BN*DK/(256*8)), dim3(256), 0, stream, x, xbf);
    hipLaunchKernelGGL((k_gemm_t<0>), dim3(GSPLIT, BN/128), dim3(512), 0, stream,
                       xbf, gmaxu, (const unsigned*)nullptr,
                       (int*)nullptr, (int*)nullptr);
    hipLaunchKernelGGL(k_tau,  dim3(BN/256), dim3(256), 0, stream,
                       gmaxu, tau_u, cnt);
    hipLaunchKernelGGL((k_gemm_t<1>), dim3(GSPLIT, BN/128), dim3(512), 0, stream,
                       xbf, (unsigned*)nullptr, tau_u, cnt, cand);
    if (ws_size >= need2) {
      // two-phase exact rescore (high-TLP score pass + light rank pass)
      hipLaunchKernelGGL(k_score, dim3(BN), dim3(512), 0, stream,
                         x, cand, cnt, svbuf);
      hipLaunchKernelGGL(k_rank,  dim3(BN/4), dim3(256), 0, stream,
                         svbuf, cand, cnt, idx);
    } else {
      // tier-2: round-13 measured combined kernel (228 us)
      hipLaunchKernelGGL(k_exact, dim3(BN/4), dim3(256), 0, stream,
                         x, cand, cnt, idx);
    }
    hipLaunchKernelGGL(k_exact_of, dim3(BN/4), dim3(256), 0, stream,
                       x, cnt, idx);
    hipLaunchKernelGGL(k_count, dim3(BN*TK/256), dim3(256), 0, stream, idx, deg);
    hipLaunchKernelGGL(k_scan,  dim3(1), dim3(1024), 0, stream, deg, off);
    hipLaunchKernelGGL(k_fill,  dim3((BN*(TK+1))/256), dim3(256), 0, stream,
                       idx, off, cur, csr);
    hipLaunchKernelGGL(k_aggr,  dim3(BN), dim3(256), 0, stream,
                       xl, xr, att, bias, off, csr, out);
  } else {
    // ---- fallback: round-3 passing pipeline (~40 MB)
    float* xl    = (float*)d_ws;
    float* xr    = xl + (size_t)BN * HC;
    int* candC   = (int*)(xr + (size_t)BN * HC);
    int* idx     = candC + (size_t)BN * NSTRIP * TK;
    int* deg     = idx + (size_t)BN * TK;
    int* off     = deg + BN;
    int* cur     = off + (BN + 1);
    int* csr     = cur + BN;
    unsigned* gmaxu_dummy = (unsigned*)(csr + (size_t)BN * (TK + 1));

    hipLaunchKernelGGL(k_init,  dim3(BN/256), dim3(256), 0, stream,
                       deg, cur, gmaxu_dummy);
    hipLaunchKernelGGL(k_lin,   dim3(BN/16),  dim3(256), 0, stream,
                       x, Wl, bl, Wr, br, xl, xr);
    hipLaunchKernelGGL(k_sim,   dim3(NSTRIP*(BN/RPB)), dim3(256), 0, stream,
                       x, candC);
    hipLaunchKernelGGL(k_rescore, dim3(BN/8), dim3(256), 0, stream,
                       x, candC, idx);
    hipLaunchKernelGGL(k_count, dim3(BN*TK/256), dim3(256), 0, stream, idx, deg);
    hipLaunchKernelGGL(k_scan,  dim3(1), dim3(1024), 0, stream, deg, off);
    hipLaunchKernelGGL(k_fill,  dim3((BN*(TK+1))/256), dim3(256), 0, stream,
                       idx, off, cur, csr);
    hipLaunchKernelGGL(k_aggr,  dim3(BN), dim3(256), 0, stream,
                       xl, xr, att, bias, off, csr, out);
  }
}